// Round 2
// baseline (975.021 us; speedup 1.0000x reference)
//
#include <hip/hip_runtime.h>
#include <hip/hip_bf16.h>

#define NPTS 65536
#define EPSV 1e-5f

typedef unsigned short ushort_t;

__device__ __forceinline__ float bf(ushort_t h) { return __uint_as_float(((unsigned)h) << 16); }
__device__ __forceinline__ ushort_t f2bf(float f) {
    unsigned u = __float_as_uint(f);
    unsigned r = (u + 0x7fffu + ((u >> 16) & 1u)) >> 16;
    return (ushort_t)r;
}

// Kernel 1: xq = x@Wq^T+bq (f32), xk = bf16(x@Wk^T+bk), xv = bf16(x@Wv^T+bv)
// one wave per point, lane = output channel
__global__ __launch_bounds__(256) void k_qkv(
    const float* __restrict__ x,
    const float* __restrict__ Wq, const float* __restrict__ bq,
    const float* __restrict__ Wk, const float* __restrict__ bk,
    const float* __restrict__ Wv, const float* __restrict__ bv,
    float* __restrict__ xq, ushort_t* __restrict__ xk, ushort_t* __restrict__ xv)
{
    const int lane = threadIdx.x & 63;
    const int n = (blockIdx.x << 2) + (threadIdx.x >> 6);

    float xval = x[n * 64 + lane];
    float aq = bq[lane], ak = bk[lane], av = bv[lane];

    const float4* wq4 = (const float4*)(Wq + (size_t)lane * 64);
    const float4* wk4 = (const float4*)(Wk + (size_t)lane * 64);
    const float4* wv4 = (const float4*)(Wv + (size_t)lane * 64);

#pragma unroll
    for (int k4 = 0; k4 < 16; ++k4) {
        float4 q = wq4[k4], kk = wk4[k4], vv = wv4[k4];
        float x0 = __shfl(xval, k4 * 4 + 0, 64);
        float x1 = __shfl(xval, k4 * 4 + 1, 64);
        float x2 = __shfl(xval, k4 * 4 + 2, 64);
        float x3 = __shfl(xval, k4 * 4 + 3, 64);
        aq = fmaf(x0, q.x, fmaf(x1, q.y, fmaf(x2, q.z, fmaf(x3, q.w, aq))));
        ak = fmaf(x0, kk.x, fmaf(x1, kk.y, fmaf(x2, kk.z, fmaf(x3, kk.w, ak))));
        av = fmaf(x0, vv.x, fmaf(x1, vv.y, fmaf(x2, vv.z, fmaf(x3, vv.w, av))));
    }
    xq[n * 64 + lane] = aq;
    xk[n * 64 + lane] = f2bf(ak);
    xv[n * 64 + lane] = f2bf(av);
}

// Kernel 2: gather + positional encoding + relation MLP + softmax + weighted sum
// one wave per point, 4 points per 256-thread block
__global__ __launch_bounds__(256) void k_attn(
    const float* __restrict__ p, const int* __restrict__ idx,
    const float* __restrict__ xq, const ushort_t* __restrict__ xk, const ushort_t* __restrict__ xv,
    const float* __restrict__ Wp1, const float* __restrict__ bp1,
    const float* __restrict__ pg, const float* __restrict__ pb,
    const float* __restrict__ pm, const float* __restrict__ pv,
    const float* __restrict__ Wp2, const float* __restrict__ bp2,
    const float* __restrict__ wg1, const float* __restrict__ wb1,
    const float* __restrict__ wm1, const float* __restrict__ wv1,
    const float* __restrict__ Ww1, const float* __restrict__ bw1,
    const float* __restrict__ wg2, const float* __restrict__ wb2,
    const float* __restrict__ wm2, const float* __restrict__ wv2,
    const float* __restrict__ Ww2, const float* __restrict__ bw2,
    float* __restrict__ out)
{
    __shared__ float sw[4][16 * 65];   // relu(bn1(w)) per wave, padded
    __shared__ float sh[4][16 * 9];    // h after Ww1+bn2+relu
    __shared__ float sww[4][16 * 9];   // logits

    const int wid = threadIdx.x >> 6;
    const int lane = threadIdx.x & 63;
    const int n = (blockIdx.x << 2) + wid;

    float* wrel = sw[wid];
    float* hb = sh[wid];
    float* wwb = sww[wid];

    // --- uniform tiny params: linear_p folded BN ---
    float w100 = Wp1[0], w101 = Wp1[1], w102 = Wp1[2];
    float w110 = Wp1[3], w111 = Wp1[4], w112 = Wp1[5];
    float w120 = Wp1[6], w121 = Wp1[7], w122 = Wp1[8];
    float sp0 = pg[0] * rsqrtf(pv[0] + EPSV);
    float sp1 = pg[1] * rsqrtf(pv[1] + EPSV);
    float sp2 = pg[2] * rsqrtf(pv[2] + EPSV);
    float off0 = (bp1[0] - pm[0]) * sp0 + pb[0];
    float off1 = (bp1[1] - pm[1]) * sp1 + pb[1];
    float off2 = (bp1[2] - pm[2]) * sp2 + pb[2];

    // --- per-channel (lane) params ---
    float xqc = xq[n * 64 + lane];
    float s1 = wg1[lane] * rsqrtf(wv1[lane] + EPSV);
    float o1 = wb1[lane] - wm1[lane] * s1;
    float wp2x = Wp2[lane * 3 + 0], wp2y = Wp2[lane * 3 + 1], wp2z = Wp2[lane * 3 + 2];
    float peb = bp2[lane];
    float pcx = p[n * 3 + 0], pcy = p[n * 3 + 1], pcz = p[n * 3 + 2];

    float vpe[16];
    const int* idxr = idx + n * 16;

    // ---- Phase A: gather, pe, relation, bn1+relu -> LDS ----
#pragma unroll
    for (int j = 0; j < 16; ++j) {
        int id = idxr[j];
        float prx = p[id * 3 + 0] - pcx;
        float pry = p[id * 3 + 1] - pcy;
        float prz = p[id * 3 + 2] - pcz;
        float t0 = fmaxf(fmaf(fmaf(prx, w100, fmaf(pry, w101, prz * w102)), sp0, off0), 0.f);
        float t1 = fmaxf(fmaf(fmaf(prx, w110, fmaf(pry, w111, prz * w112)), sp1, off1), 0.f);
        float t2 = fmaxf(fmaf(fmaf(prx, w120, fmaf(pry, w121, prz * w122)), sp2, off2), 0.f);
        float pe = fmaf(t0, wp2x, fmaf(t1, wp2y, fmaf(t2, wp2z, peb)));
        float kv = bf(xk[(size_t)id * 64 + lane]);
        float vv = bf(xv[(size_t)id * 64 + lane]);
        vpe[j] = vv + pe;
        float w = kv - xqc + pe;
        wrel[j * 65 + lane] = fmaxf(fmaf(w, s1, o1), 0.f);
    }
    __syncthreads();

    // ---- Phase B: w @ Ww1^T -> bn2+relu -> @ Ww2^T ----
    const int m = lane & 7;
    const int j0 = lane >> 3;
    float s2 = wg2[m] * rsqrtf(wv2[m] + EPSV);
    float o2 = wb2[m] - wm2[m] * s2;
    float bw1v = bw1[m];
    const float4* w1row = (const float4*)(Ww1 + (size_t)m * 64);

#pragma unroll
    for (int pi = 0; pi < 2; ++pi) {
        int j = j0 + pi * 8;
        float acc = bw1v;
        const float* wr = wrel + j * 65;
#pragma unroll
        for (int c4 = 0; c4 < 16; ++c4) {
            float4 u = w1row[c4];
            const float* r = wr + c4 * 4;
            acc = fmaf(r[0], u.x, fmaf(r[1], u.y, fmaf(r[2], u.z, fmaf(r[3], u.w, acc))));
        }
        hb[j * 9 + m] = fmaxf(fmaf(acc, s2, o2), 0.f);
    }
    __syncthreads();

    float w2r[8];
#pragma unroll
    for (int mm = 0; mm < 8; ++mm) w2r[mm] = Ww2[m * 8 + mm];
    float bw2v = bw2[m];
#pragma unroll
    for (int pi = 0; pi < 2; ++pi) {
        int j = j0 + pi * 8;
        float acc = bw2v;
#pragma unroll
        for (int mm = 0; mm < 8; ++mm) acc = fmaf(hb[j * 9 + mm], w2r[mm], acc);
        wwb[j * 9 + m] = acc;
    }
    __syncthreads();

    // ---- Phase C: softmax over neighbors (per m = lane&7), weighted sum ----
    float mx = -1e30f;
    float e[16];
#pragma unroll
    for (int j = 0; j < 16; ++j) { e[j] = wwb[j * 9 + m]; mx = fmaxf(mx, e[j]); }
    float ssum = 0.f;
#pragma unroll
    for (int j = 0; j < 16; ++j) { e[j] = __expf(e[j] - mx); ssum += e[j]; }
    float inv = 1.f / ssum;
    float acc = 0.f;
#pragma unroll
    for (int j = 0; j < 16; ++j) acc = fmaf(vpe[j], e[j], acc);
    out[n * 64 + lane] = acc * inv;
}

extern "C" void kernel_launch(void* const* d_in, const int* in_sizes, int n_in,
                              void* d_out, int out_size, void* d_ws, size_t ws_size,
                              hipStream_t stream) {
    const float* p   = (const float*)d_in[0];
    const float* x   = (const float*)d_in[1];
    const int*   idx = (const int*)d_in[2];
    const float* Wq  = (const float*)d_in[3];  const float* bq  = (const float*)d_in[4];
    const float* Wk  = (const float*)d_in[5];  const float* bk  = (const float*)d_in[6];
    const float* Wv  = (const float*)d_in[7];  const float* bv  = (const float*)d_in[8];
    const float* Wp1 = (const float*)d_in[9];  const float* bp1 = (const float*)d_in[10];
    const float* pg  = (const float*)d_in[11]; const float* pb  = (const float*)d_in[12];
    const float* pm  = (const float*)d_in[13]; const float* pv  = (const float*)d_in[14];
    const float* Wp2 = (const float*)d_in[15]; const float* bp2 = (const float*)d_in[16];
    const float* wg1 = (const float*)d_in[17]; const float* wb1 = (const float*)d_in[18];
    const float* wm1 = (const float*)d_in[19]; const float* wv1 = (const float*)d_in[20];
    const float* Ww1 = (const float*)d_in[21]; const float* bw1 = (const float*)d_in[22];
    const float* wg2 = (const float*)d_in[23]; const float* wb2 = (const float*)d_in[24];
    const float* wm2 = (const float*)d_in[25]; const float* wv2 = (const float*)d_in[26];
    const float* Ww2 = (const float*)d_in[27]; const float* bw2 = (const float*)d_in[28];

    float*    xqw = (float*)d_ws;
    ushort_t* xkw = (ushort_t*)((char*)d_ws + (size_t)NPTS * 64 * sizeof(float));
    ushort_t* xvw = xkw + (size_t)NPTS * 64;
    float*    outp = (float*)d_out;

    k_qkv<<<dim3(NPTS / 4), dim3(256), 0, stream>>>(x, Wq, bq, Wk, bk, Wv, bv, xqw, xkw, xvw);
    k_attn<<<dim3(NPTS / 4), dim3(256), 0, stream>>>(p, idx, xqw, xkw, xvw,
                                                     Wp1, bp1, pg, pb, pm, pv, Wp2, bp2,
                                                     wg1, wb1, wm1, wv1, Ww1, bw1,
                                                     wg2, wb2, wm2, wv2, Ww2, bw2, outp);
}

// Round 3
// 800.691 us; speedup vs baseline: 1.2177x; 1.2177x over previous
//
#include <hip/hip_runtime.h>

#define NPTS 65536
#define EPSV 1e-5f

typedef unsigned int uint_t;
typedef unsigned short ushort_t;

__device__ __forceinline__ ushort_t f2bf(float f) {
    unsigned u = __float_as_uint(f);
    unsigned r = (u + 0x7fffu + ((u >> 16) & 1u)) >> 16;
    return (ushort_t)r;
}

// ---------------------------------------------------------------------------
// Kernel 1: xq = x@Wq^T+bq (f32), kv = pack(bf16(x@Wk^T+bk), bf16(x@Wv^T+bv))
// Block = 256 threads = 4 waves; block covers 64 points; wave w computes
// output channels [w*16, w*16+16) of q, k, v for all 64 points.
// Weight indices are wave-uniform (readfirstlane) -> scalar s_loads via K$.
// Outputs transposed through LDS so global stores are coalesced.
// ---------------------------------------------------------------------------
__global__ __launch_bounds__(256, 4) void k_qkv(
    const float* __restrict__ x,
    const float* __restrict__ Wq, const float* __restrict__ bq,
    const float* __restrict__ Wk, const float* __restrict__ bk,
    const float* __restrict__ Wv, const float* __restrict__ bv,
    float* __restrict__ xq, uint_t* __restrict__ kvp)
{
    __shared__ float  xqt[64][65];
    __shared__ uint_t kvt[64][65];

    const int tid  = threadIdx.x;
    const int lane = tid & 63;
    const int w    = __builtin_amdgcn_readfirstlane(tid >> 6);  // output group, wave-uniform
    const int n0   = blockIdx.x * 64;

    // per-lane x row (256 B)
    const float4* xrow = (const float4*)(x + (size_t)(n0 + lane) * 64);
    float4 xr[16];
#pragma unroll
    for (int i = 0; i < 16; ++i) xr[i] = xrow[i];

#pragma unroll 2
    for (int oi = 0; oi < 16; ++oi) {
        const int o = w * 16 + oi;                 // wave-uniform
        const float4* wq4 = (const float4*)(Wq + o * 64);
        const float4* wk4 = (const float4*)(Wk + o * 64);
        const float4* wv4 = (const float4*)(Wv + o * 64);
        float aq = bq[o], ak = bk[o], av = bv[o];
#pragma unroll
        for (int c = 0; c < 16; ++c) {
            float4 q = wq4[c], k = wk4[c], v = wv4[c];
            float4 xv4 = xr[c];
            aq = fmaf(xv4.x, q.x, fmaf(xv4.y, q.y, fmaf(xv4.z, q.z, fmaf(xv4.w, q.w, aq))));
            ak = fmaf(xv4.x, k.x, fmaf(xv4.y, k.y, fmaf(xv4.z, k.z, fmaf(xv4.w, k.w, ak))));
            av = fmaf(xv4.x, v.x, fmaf(xv4.y, v.y, fmaf(xv4.z, v.z, fmaf(xv4.w, v.w, av))));
        }
        xqt[lane][o] = aq;
        kvt[lane][o] = (uint_t)f2bf(ak) | ((uint_t)f2bf(av) << 16);
    }
    __syncthreads();

    // coalesced store: 16 rows of 256 consecutive elements per iteration
#pragma unroll
    for (int it = 0; it < 16; ++it) {
        int f = it * 256 + tid;
        int r = f >> 6, c = f & 63;
        xq[(size_t)(n0 + r) * 64 + c]  = xqt[r][c];
        kvp[(size_t)(n0 + r) * 64 + c] = kvt[r][c];
    }
}

// ---------------------------------------------------------------------------
// Kernel 2: gather + positional encoding + relation MLP + softmax + sum
// one wave per point, 4 points per block. All 16 kv-gathers issued into a
// register array before first use (deep MLP); p handled lane-parallel.
// ---------------------------------------------------------------------------
__global__ __launch_bounds__(256, 5) void k_attn(
    const float* __restrict__ p, const int* __restrict__ idx,
    const float* __restrict__ xq, const uint_t* __restrict__ kvp,
    const float* __restrict__ Wp1, const float* __restrict__ bp1,
    const float* __restrict__ pg, const float* __restrict__ pb,
    const float* __restrict__ pm, const float* __restrict__ pv,
    const float* __restrict__ Wp2, const float* __restrict__ bp2,
    const float* __restrict__ wg1, const float* __restrict__ wb1,
    const float* __restrict__ wm1, const float* __restrict__ wv1,
    const float* __restrict__ Ww1, const float* __restrict__ bw1,
    const float* __restrict__ wg2, const float* __restrict__ wb2,
    const float* __restrict__ wm2, const float* __restrict__ wv2,
    const float* __restrict__ Ww2, const float* __restrict__ bw2,
    float* __restrict__ out)
{
    __shared__ float  sw[4][16 * 65];    // relu(bn1(w)) per wave, padded
    __shared__ float4 swt[4][16];        // t-triples per wave
    __shared__ float  sh[4][16 * 9];     // h after Ww1+bn2+relu
    __shared__ float  sww[4][16 * 9];    // logits

    const int wid  = threadIdx.x >> 6;
    const int lane = threadIdx.x & 63;
    const int n    = (blockIdx.x << 2) + wid;

    float* wrel = sw[wid];
    float* hb   = sh[wid];
    float* wwb  = sww[wid];

    const int* idxr = idx + n * 16;

    // --- issue ALL independent loads up front ---
    const int4* i4 = (const int4*)idxr;
    int4 ia = i4[0], ib = i4[1], ic = i4[2], id4 = i4[3];
    int idp = idxr[lane & 15];                    // index for this lane's j-slot
    float pcx = p[n * 3 + 0], pcy = p[n * 3 + 1], pcz = p[n * 3 + 2];
    float xqc = xq[n * 64 + lane];

    uint_t g[16];
    {
        const size_t ln = lane;
        g[0]  = kvp[(size_t)ia.x  * 64 + ln]; g[1]  = kvp[(size_t)ia.y  * 64 + ln];
        g[2]  = kvp[(size_t)ia.z  * 64 + ln]; g[3]  = kvp[(size_t)ia.w  * 64 + ln];
        g[4]  = kvp[(size_t)ib.x  * 64 + ln]; g[5]  = kvp[(size_t)ib.y  * 64 + ln];
        g[6]  = kvp[(size_t)ib.z  * 64 + ln]; g[7]  = kvp[(size_t)ib.w  * 64 + ln];
        g[8]  = kvp[(size_t)ic.x  * 64 + ln]; g[9]  = kvp[(size_t)ic.y  * 64 + ln];
        g[10] = kvp[(size_t)ic.z  * 64 + ln]; g[11] = kvp[(size_t)ic.w  * 64 + ln];
        g[12] = kvp[(size_t)id4.x * 64 + ln]; g[13] = kvp[(size_t)id4.y * 64 + ln];
        g[14] = kvp[(size_t)id4.z * 64 + ln]; g[15] = kvp[(size_t)id4.w * 64 + ln];
    }

    // lane-parallel p gather for j = lane&15 (4x redundant across lane quads)
    float px = p[idp * 3 + 0], py = p[idp * 3 + 1], pz = p[idp * 3 + 2];

    // --- tiny uniform params (linear_p with folded BN) ---
    float w100 = Wp1[0], w101 = Wp1[1], w102 = Wp1[2];
    float w110 = Wp1[3], w111 = Wp1[4], w112 = Wp1[5];
    float w120 = Wp1[6], w121 = Wp1[7], w122 = Wp1[8];
    float sp0 = pg[0] * rsqrtf(pv[0] + EPSV);
    float sp1 = pg[1] * rsqrtf(pv[1] + EPSV);
    float sp2 = pg[2] * rsqrtf(pv[2] + EPSV);
    float off0 = (bp1[0] - pm[0]) * sp0 + pb[0];
    float off1 = (bp1[1] - pm[1]) * sp1 + pb[1];
    float off2 = (bp1[2] - pm[2]) * sp2 + pb[2];

    // --- per-channel (lane) params ---
    float s1 = wg1[lane] * rsqrtf(wv1[lane] + EPSV);
    float o1 = wb1[lane] - wm1[lane] * s1;
    float wp2x = Wp2[lane * 3 + 0], wp2y = Wp2[lane * 3 + 1], wp2z = Wp2[lane * 3 + 2];
    float peb = bp2[lane];

    // t-triple for this lane's j-slot, broadcast via per-wave LDS
    {
        float prx = px - pcx, pry = py - pcy, prz = pz - pcz;
        float t0 = fmaxf(fmaf(fmaf(prx, w100, fmaf(pry, w101, prz * w102)), sp0, off0), 0.f);
        float t1 = fmaxf(fmaf(fmaf(prx, w110, fmaf(pry, w111, prz * w112)), sp1, off1), 0.f);
        float t2 = fmaxf(fmaf(fmaf(prx, w120, fmaf(pry, w121, prz * w122)), sp2, off2), 0.f);
        if (lane < 16) swt[wid][lane] = make_float4(t0, t1, t2, 0.f);
    }

    // ---- Phase A: pe + relation + bn1+relu -> LDS ----
    float vpe[16];
#pragma unroll
    for (int j = 0; j < 16; ++j) {
        float4 t = swt[wid][j];
        float pe = fmaf(t.x, wp2x, fmaf(t.y, wp2y, fmaf(t.z, wp2z, peb)));
        float xkj = __uint_as_float(g[j] << 16);
        float xvj = __uint_as_float(g[j] & 0xffff0000u);
        vpe[j] = xvj + pe;
        float wv_ = xkj - xqc + pe;
        wrel[j * 65 + lane] = fmaxf(fmaf(wv_, s1, o1), 0.f);
    }
    __syncthreads();

    // ---- Phase B: w @ Ww1^T -> bn2+relu -> @ Ww2^T ----
    const int m = lane & 7;
    const int j0 = lane >> 3;
    float s2 = wg2[m] * rsqrtf(wv2[m] + EPSV);
    float o2 = wb2[m] - wm2[m] * s2;
    float bw1v = bw1[m];
    const float4* w1row = (const float4*)(Ww1 + (size_t)m * 64);

#pragma unroll
    for (int pi = 0; pi < 2; ++pi) {
        int j = j0 + pi * 8;
        float acc = bw1v;
        const float* wr = wrel + j * 65;
#pragma unroll
        for (int c4 = 0; c4 < 16; ++c4) {
            float4 u = w1row[c4];
            const float* r = wr + c4 * 4;
            acc = fmaf(r[0], u.x, fmaf(r[1], u.y, fmaf(r[2], u.z, fmaf(r[3], u.w, acc))));
        }
        hb[j * 9 + m] = fmaxf(fmaf(acc, s2, o2), 0.f);
    }
    __syncthreads();

    float w2r[8];
#pragma unroll
    for (int mm = 0; mm < 8; ++mm) w2r[mm] = Ww2[m * 8 + mm];
    float bw2v = bw2[m];
#pragma unroll
    for (int pi = 0; pi < 2; ++pi) {
        int j = j0 + pi * 8;
        float acc = bw2v;
#pragma unroll
        for (int mm = 0; mm < 8; ++mm) acc = fmaf(hb[j * 9 + mm], w2r[mm], acc);
        wwb[j * 9 + m] = acc;
    }
    __syncthreads();

    // ---- Phase C: softmax over neighbors (per m = lane&7), weighted sum ----
    float mx = -1e30f;
    float e[16];
#pragma unroll
    for (int j = 0; j < 16; ++j) { e[j] = wwb[j * 9 + m]; mx = fmaxf(mx, e[j]); }
    float ssum = 0.f;
#pragma unroll
    for (int j = 0; j < 16; ++j) { e[j] = __expf(e[j] - mx); ssum += e[j]; }
    float inv = 1.f / ssum;
    float acc = 0.f;
#pragma unroll
    for (int j = 0; j < 16; ++j) acc = fmaf(vpe[j], e[j], acc);
    out[n * 64 + lane] = acc * inv;
}

extern "C" void kernel_launch(void* const* d_in, const int* in_sizes, int n_in,
                              void* d_out, int out_size, void* d_ws, size_t ws_size,
                              hipStream_t stream) {
    const float* p   = (const float*)d_in[0];
    const float* x   = (const float*)d_in[1];
    const int*   idx = (const int*)d_in[2];
    const float* Wq  = (const float*)d_in[3];  const float* bq  = (const float*)d_in[4];
    const float* Wk  = (const float*)d_in[5];  const float* bk  = (const float*)d_in[6];
    const float* Wv  = (const float*)d_in[7];  const float* bv  = (const float*)d_in[8];
    const float* Wp1 = (const float*)d_in[9];  const float* bp1 = (const float*)d_in[10];
    const float* pg  = (const float*)d_in[11]; const float* pb  = (const float*)d_in[12];
    const float* pm  = (const float*)d_in[13]; const float* pv  = (const float*)d_in[14];
    const float* Wp2 = (const float*)d_in[15]; const float* bp2 = (const float*)d_in[16];
    const float* wg1 = (const float*)d_in[17]; const float* wb1 = (const float*)d_in[18];
    const float* wm1 = (const float*)d_in[19]; const float* wv1 = (const float*)d_in[20];
    const float* Ww1 = (const float*)d_in[21]; const float* bw1 = (const float*)d_in[22];
    const float* wg2 = (const float*)d_in[23]; const float* wb2 = (const float*)d_in[24];
    const float* wm2 = (const float*)d_in[25]; const float* wv2 = (const float*)d_in[26];
    const float* Ww2 = (const float*)d_in[27]; const float* bw2 = (const float*)d_in[28];

    float*  xqw = (float*)d_ws;
    uint_t* kvw = (uint_t*)((char*)d_ws + (size_t)NPTS * 64 * sizeof(float));
    float*  outp = (float*)d_out;

    k_qkv<<<dim3(NPTS / 64), dim3(256), 0, stream>>>(x, Wq, bq, Wk, bk, Wv, bv, xqw, kvw);
    k_attn<<<dim3(NPTS / 4), dim3(256), 0, stream>>>(p, idx, xqw, kvw,
                                                     Wp1, bp1, pg, pb, pm, pv, Wp2, bp2,
                                                     wg1, wb1, wm1, wv1, Ww1, bw1,
                                                     wg2, wb2, wm2, wv2, Ww2, bw2, outp);
}

// Round 4
// 528.128 us; speedup vs baseline: 1.8462x; 1.5161x over previous
//
#include <hip/hip_runtime.h>

#define NPTS 65536
#define EPSV 1e-5f

typedef unsigned int uint_t;
typedef unsigned short ushort_t;

__device__ __forceinline__ ushort_t f2bf(float f) {
    unsigned u = __float_as_uint(f);
    unsigned r = (u + 0x7fffu + ((u >> 16) & 1u)) >> 16;
    return (ushort_t)r;
}

// ---------------------------------------------------------------------------
// Kernel 1: xq = x@Wq^T+bq (f32), kv = pack(bf16(x@Wk^T+bk), bf16(x@Wv^T+bv))
// Block = 256 = 4 waves over 64 points; wave w -> output channels [16w,16w+16).
// Wave-uniform weight addressing -> scalar K$ loads. No VGPR cap (avoid spill).
// ---------------------------------------------------------------------------
__global__ __launch_bounds__(256) void k_qkv(
    const float* __restrict__ x,
    const float* __restrict__ Wq, const float* __restrict__ bq,
    const float* __restrict__ Wk, const float* __restrict__ bk,
    const float* __restrict__ Wv, const float* __restrict__ bv,
    float* __restrict__ xq, uint_t* __restrict__ kvp)
{
    __shared__ float  xqt[64][65];
    __shared__ uint_t kvt[64][65];

    const int tid  = threadIdx.x;
    const int lane = tid & 63;
    const int w    = __builtin_amdgcn_readfirstlane(tid >> 6);
    const int n0   = blockIdx.x * 64;

    const float4* xrow = (const float4*)(x + (size_t)(n0 + lane) * 64);
    float4 xr[16];
#pragma unroll
    for (int i = 0; i < 16; ++i) xr[i] = xrow[i];

#pragma unroll 2
    for (int oi = 0; oi < 16; ++oi) {
        const int o = w * 16 + oi;                 // wave-uniform
        const float4* wq4 = (const float4*)(Wq + o * 64);
        const float4* wk4 = (const float4*)(Wk + o * 64);
        const float4* wv4 = (const float4*)(Wv + o * 64);
        float aq = bq[o], ak = bk[o], av = bv[o];
#pragma unroll
        for (int c = 0; c < 16; ++c) {
            float4 q = wq4[c], k = wk4[c], v = wv4[c];
            float4 xv4 = xr[c];
            aq = fmaf(xv4.x, q.x, fmaf(xv4.y, q.y, fmaf(xv4.z, q.z, fmaf(xv4.w, q.w, aq))));
            ak = fmaf(xv4.x, k.x, fmaf(xv4.y, k.y, fmaf(xv4.z, k.z, fmaf(xv4.w, k.w, ak))));
            av = fmaf(xv4.x, v.x, fmaf(xv4.y, v.y, fmaf(xv4.z, v.z, fmaf(xv4.w, v.w, av))));
        }
        xqt[lane][o] = aq;
        kvt[lane][o] = (uint_t)f2bf(ak) | ((uint_t)f2bf(av) << 16);
    }
    __syncthreads();

#pragma unroll
    for (int it = 0; it < 16; ++it) {
        int f = it * 256 + tid;
        int r = f >> 6, c = f & 63;
        xq[(size_t)(n0 + r) * 64 + c]  = xqt[r][c];
        kvp[(size_t)(n0 + r) * 64 + c] = kvt[r][c];
    }
}

// ---------------------------------------------------------------------------
// Kernel 2: one wave per 4-point strip; barrier-free (wave-private LDS),
// 2-deep software-pipelined kv gathers across points.
// ---------------------------------------------------------------------------
__global__ __launch_bounds__(256, 4) void k_attn(
    const float* __restrict__ p, const int* __restrict__ idx,
    const float* __restrict__ xq, const uint_t* __restrict__ kvp,
    const float* __restrict__ Wp1, const float* __restrict__ bp1,
    const float* __restrict__ pg, const float* __restrict__ pb,
    const float* __restrict__ pm, const float* __restrict__ pv,
    const float* __restrict__ Wp2, const float* __restrict__ bp2,
    const float* __restrict__ wg1, const float* __restrict__ wb1,
    const float* __restrict__ wm1, const float* __restrict__ wv1,
    const float* __restrict__ Ww1, const float* __restrict__ bw1,
    const float* __restrict__ wg2, const float* __restrict__ wb2,
    const float* __restrict__ wm2, const float* __restrict__ wv2,
    const float* __restrict__ Ww2, const float* __restrict__ bw2,
    float* __restrict__ out)
{
    __shared__ float sw[4][16 * 65];    // per-wave wrel (private slices)
    __shared__ float sh[4][16 * 9];     // per-wave h
    __shared__ float sww[4][16 * 9];    // per-wave logits

    const int wid   = __builtin_amdgcn_readfirstlane(threadIdx.x >> 6);
    const int lane  = threadIdx.x & 63;
    const int nbase = blockIdx.x * 16 + wid * 4;   // 4 points per wave

    float* wrel = sw[wid];
    float* hb   = sh[wid];
    float* wwb  = sww[wid];

    // ---- uniform tiny params (linear_p with folded BN) ----
    float w100 = Wp1[0], w101 = Wp1[1], w102 = Wp1[2];
    float w110 = Wp1[3], w111 = Wp1[4], w112 = Wp1[5];
    float w120 = Wp1[6], w121 = Wp1[7], w122 = Wp1[8];
    float sp0 = pg[0] * rsqrtf(pv[0] + EPSV);
    float sp1 = pg[1] * rsqrtf(pv[1] + EPSV);
    float sp2 = pg[2] * rsqrtf(pv[2] + EPSV);
    float off0 = (bp1[0] - pm[0]) * sp0 + pb[0];
    float off1 = (bp1[1] - pm[1]) * sp1 + pb[1];
    float off2 = (bp1[2] - pm[2]) * sp2 + pb[2];

    // ---- per-lane params (hoisted across the whole strip) ----
    float s1 = wg1[lane] * rsqrtf(wv1[lane] + EPSV);
    float o1 = wb1[lane] - wm1[lane] * s1;
    float wp2x = Wp2[lane * 3 + 0], wp2y = Wp2[lane * 3 + 1], wp2z = Wp2[lane * 3 + 2];
    float peb = bp2[lane];

    const int m  = lane & 7;
    const int j0 = lane >> 3;
    float s2 = wg2[m] * rsqrtf(wv2[m] + EPSV);
    float o2 = wb2[m] - wm2[m] * s2;
    float bw1v = bw1[m];
    float bw2v = bw2[m];
    float w2r[8];
#pragma unroll
    for (int mm = 0; mm < 8; ++mm) w2r[mm] = Ww2[m * 8 + mm];
    const float4* w1row = (const float4*)(Ww1 + (size_t)m * 64);

    const int* idxr = idx + (size_t)nbase * 16;    // wave-uniform base

    // ---- upfront strip loads: idx (vector, for p-gather), centers, xq ----
    int   idv[4];
    float xqc[4];
#pragma unroll
    for (int pt = 0; pt < 4; ++pt) {
        idv[pt] = idxr[pt * 16 + (lane & 15)];
        xqc[pt] = xq[(size_t)(nbase + pt) * 64 + lane];
    }
    float gpx[4], gpy[4], gpz[4];
#pragma unroll
    for (int pt = 0; pt < 4; ++pt) {
        gpx[pt] = p[idv[pt] * 3 + 0];
        gpy[pt] = p[idv[pt] * 3 + 1];
        gpz[pt] = p[idv[pt] * 3 + 2];
    }

    // ---- t-triples per point (lane slot = lane&15), kept in registers ----
    float t0a[4], t1a[4], t2a[4];
#pragma unroll
    for (int pt = 0; pt < 4; ++pt) {
        int n = nbase + pt;
        float pcx = p[n * 3 + 0], pcy = p[n * 3 + 1], pcz = p[n * 3 + 2];
        float prx = gpx[pt] - pcx, pry = gpy[pt] - pcy, prz = gpz[pt] - pcz;
        t0a[pt] = fmaxf(fmaf(fmaf(prx, w100, fmaf(pry, w101, prz * w102)), sp0, off0), 0.f);
        t1a[pt] = fmaxf(fmaf(fmaf(prx, w110, fmaf(pry, w111, prz * w112)), sp1, off1), 0.f);
        t2a[pt] = fmaxf(fmaf(fmaf(prx, w120, fmaf(pry, w121, prz * w122)), sp2, off2), 0.f);
    }

    uint_t ga[16], gb[16];

    auto issueF = [&](int pt, uint_t (&dst)[16]) {
#pragma unroll
        for (int j = 0; j < 16; ++j) {
            int id = __builtin_amdgcn_readfirstlane(idxr[pt * 16 + j]);
            dst[j] = kvp[(size_t)id * 64 + lane];
        }
    };

    auto computeF = [&](int pt, uint_t (&g)[16]) {
        float t0v = t0a[pt], t1v = t1a[pt], t2v = t2a[pt];
        float xqv = xqc[pt];
        float vpe[16];
        // Phase A: pe + relation + bn1+relu -> wrel
#pragma unroll
        for (int j = 0; j < 16; ++j) {
            float tt0 = __shfl(t0v, j, 64);
            float tt1 = __shfl(t1v, j, 64);
            float tt2 = __shfl(t2v, j, 64);
            float pe = fmaf(tt0, wp2x, fmaf(tt1, wp2y, fmaf(tt2, wp2z, peb)));
            float xkj = __uint_as_float(g[j] << 16);
            float xvj = __uint_as_float(g[j] & 0xffff0000u);
            vpe[j] = xvj + pe;
            wrel[j * 65 + lane] = fmaxf(fmaf(xkj - xqv + pe, s1, o1), 0.f);
        }
        asm volatile("s_waitcnt lgkmcnt(0)" ::: "memory");
        __builtin_amdgcn_wave_barrier();

        // Phase B1: w @ Ww1^T -> bn2+relu
#pragma unroll
        for (int pi = 0; pi < 2; ++pi) {
            int j = j0 + pi * 8;
            float acc = bw1v;
            const float* wr = wrel + j * 65;
#pragma unroll
            for (int c4 = 0; c4 < 16; ++c4) {
                float4 u = w1row[c4];
                const float* r = wr + c4 * 4;
                acc = fmaf(r[0], u.x, fmaf(r[1], u.y, fmaf(r[2], u.z, fmaf(r[3], u.w, acc))));
            }
            hb[j * 9 + m] = fmaxf(fmaf(acc, s2, o2), 0.f);
        }
        asm volatile("s_waitcnt lgkmcnt(0)" ::: "memory");
        __builtin_amdgcn_wave_barrier();

        // Phase B2: @ Ww2^T -> logits
#pragma unroll
        for (int pi = 0; pi < 2; ++pi) {
            int j = j0 + pi * 8;
            float acc = bw2v;
#pragma unroll
            for (int mm = 0; mm < 8; ++mm) acc = fmaf(hb[j * 9 + mm], w2r[mm], acc);
            wwb[j * 9 + m] = acc;
        }
        asm volatile("s_waitcnt lgkmcnt(0)" ::: "memory");
        __builtin_amdgcn_wave_barrier();

        // Phase C: softmax over neighbors + weighted sum
        float mx = -1e30f;
        float e[16];
#pragma unroll
        for (int j = 0; j < 16; ++j) { e[j] = wwb[j * 9 + m]; mx = fmaxf(mx, e[j]); }
        float ssum = 0.f;
#pragma unroll
        for (int j = 0; j < 16; ++j) { e[j] = __expf(e[j] - mx); ssum += e[j]; }
        float inv = 1.f / ssum;
        float acc = 0.f;
#pragma unroll
        for (int j = 0; j < 16; ++j) acc = fmaf(vpe[j], e[j], acc);
        out[(size_t)(nbase + pt) * 64 + lane] = acc * inv;
    };

    // 2-deep pipelined strip
    issueF(0, ga);
    issueF(1, gb);
    computeF(0, ga);
    issueF(2, ga);
    computeF(1, gb);
    issueF(3, gb);
    computeF(2, ga);
    computeF(3, gb);
}

extern "C" void kernel_launch(void* const* d_in, const int* in_sizes, int n_in,
                              void* d_out, int out_size, void* d_ws, size_t ws_size,
                              hipStream_t stream) {
    const float* p   = (const float*)d_in[0];
    const float* x   = (const float*)d_in[1];
    const int*   idx = (const int*)d_in[2];
    const float* Wq  = (const float*)d_in[3];  const float* bq  = (const float*)d_in[4];
    const float* Wk  = (const float*)d_in[5];  const float* bk  = (const float*)d_in[6];
    const float* Wv  = (const float*)d_in[7];  const float* bv  = (const float*)d_in[8];
    const float* Wp1 = (const float*)d_in[9];  const float* bp1 = (const float*)d_in[10];
    const float* pg  = (const float*)d_in[11]; const float* pb  = (const float*)d_in[12];
    const float* pm  = (const float*)d_in[13]; const float* pv  = (const float*)d_in[14];
    const float* Wp2 = (const float*)d_in[15]; const float* bp2 = (const float*)d_in[16];
    const float* wg1 = (const float*)d_in[17]; const float* wb1 = (const float*)d_in[18];
    const float* wm1 = (const float*)d_in[19]; const float* wv1 = (const float*)d_in[20];
    const float* Ww1 = (const float*)d_in[21]; const float* bw1 = (const float*)d_in[22];
    const float* wg2 = (const float*)d_in[23]; const float* wb2 = (const float*)d_in[24];
    const float* wm2 = (const float*)d_in[25]; const float* wv2 = (const float*)d_in[26];
    const float* Ww2 = (const float*)d_in[27]; const float* bw2 = (const float*)d_in[28];

    float*  xqw = (float*)d_ws;
    uint_t* kvw = (uint_t*)((char*)d_ws + (size_t)NPTS * 64 * sizeof(float));
    float*  outp = (float*)d_out;

    k_qkv<<<dim3(NPTS / 64), dim3(256), 0, stream>>>(x, Wq, bq, Wk, bk, Wv, bv, xqw, kvw);
    k_attn<<<dim3(NPTS / 16), dim3(256), 0, stream>>>(p, idx, xqw, kvw,
                                                      Wp1, bp1, pg, pb, pm, pv, Wp2, bp2,
                                                      wg1, wb1, wm1, wv1, Ww1, bw1,
                                                      wg2, wb2, wm2, wv2, Ww2, bw2, outp);
}

// Round 5
// 425.212 us; speedup vs baseline: 2.2930x; 1.2420x over previous
//
#include <hip/hip_runtime.h>

#define NPTS 65536
#define EPSV 1e-5f

typedef unsigned int uint_t;
typedef unsigned short ushort_t;

__device__ __forceinline__ ushort_t f2bf(float f) {
    unsigned u = __float_as_uint(f);
    unsigned r = (u + 0x7fffu + ((u >> 16) & 1u)) >> 16;
    return (ushort_t)r;
}

__device__ __forceinline__ float rdlane(float v, int j) {
    return __uint_as_float(__builtin_amdgcn_readlane(__float_as_uint(v), j));
}

// ---------------------------------------------------------------------------
// Kernel 1: xq = x@Wq^T+bq (f32), kv = pack(bf16(k), bf16(v))
// Block = 256 = 4 waves over 64 points; wave w -> out channels [16w,16w+16).
// x tile loaded COALESCED into XOR-swizzled LDS, then per-lane row reads.
// Weights via wave-uniform scalar loads (K$). Output transposed through LDS.
// ---------------------------------------------------------------------------
__global__ __launch_bounds__(256) void k_qkv(
    const float* __restrict__ x,
    const float* __restrict__ Wq, const float* __restrict__ bq,
    const float* __restrict__ Wk, const float* __restrict__ bk,
    const float* __restrict__ Wv, const float* __restrict__ bv,
    float* __restrict__ xq, uint_t* __restrict__ kvp)
{
    __shared__ __align__(16) char smem[64 * 65 * 4 + 64 * 65 * 4];
    float*  sx  = (float*)smem;                       // 16 KB swizzled x tile
    float*  xqt = (float*)smem;                       // [64][65] (aliases sx)
    uint_t* kvt = (uint_t*)(smem + 64 * 65 * 4);      // [64][65]

    const int tid  = threadIdx.x;
    const int lane = tid & 63;
    const int w    = __builtin_amdgcn_readfirstlane(tid >> 6);
    const int n0   = blockIdx.x * 64;

    // coalesced load of 64x64 f32 tile -> swizzled LDS
    const float4* xg = (const float4*)(x + (size_t)n0 * 64);
#pragma unroll
    for (int k = 0; k < 4; ++k) {
        int f = k * 256 + tid;            // float4 index 0..1023
        int r = f >> 4, c = f & 15;
        float4 v = xg[f];
        *((float4*)(sx + r * 64 + ((c ^ (r & 15)) << 2))) = v;
    }
    __syncthreads();

    // per-lane row gather from LDS (conflict-free b128)
    float4 xr[16];
#pragma unroll
    for (int i = 0; i < 16; ++i)
        xr[i] = *((const float4*)(sx + lane * 64 + ((i ^ (lane & 15)) << 2)));
    __syncthreads();   // all reads done before xqt overlays sx

#pragma unroll 2
    for (int oi = 0; oi < 16; ++oi) {
        const int o = w * 16 + oi;                    // wave-uniform
        const float4* wq4 = (const float4*)(Wq + o * 64);
        const float4* wk4 = (const float4*)(Wk + o * 64);
        const float4* wv4 = (const float4*)(Wv + o * 64);
        float aq = bq[o], ak = bk[o], av = bv[o];
#pragma unroll
        for (int c = 0; c < 16; ++c) {
            float4 q = wq4[c], k = wk4[c], v = wv4[c];
            float4 xv4 = xr[c];
            aq = fmaf(xv4.x, q.x, fmaf(xv4.y, q.y, fmaf(xv4.z, q.z, fmaf(xv4.w, q.w, aq))));
            ak = fmaf(xv4.x, k.x, fmaf(xv4.y, k.y, fmaf(xv4.z, k.z, fmaf(xv4.w, k.w, ak))));
            av = fmaf(xv4.x, v.x, fmaf(xv4.y, v.y, fmaf(xv4.z, v.z, fmaf(xv4.w, v.w, av))));
        }
        xqt[lane * 65 + o] = aq;
        kvt[lane * 65 + o] = (uint_t)f2bf(ak) | ((uint_t)f2bf(av) << 16);
    }
    __syncthreads();

#pragma unroll
    for (int it = 0; it < 16; ++it) {
        int f = it * 256 + tid;
        int r = f >> 6, c = f & 63;
        xq[(size_t)(n0 + r) * 64 + c]  = xqt[r * 65 + c];
        kvp[(size_t)(n0 + r) * 64 + c] = kvt[r * 65 + c];
    }
}

// ---------------------------------------------------------------------------
// Kernel 2: one wave per 4-point strip; barrier-free after Ww1 staging;
// kv gathers issued BEFORE t-triple math; Ww1 in block LDS; stride-68 b128.
// ---------------------------------------------------------------------------
__global__ __launch_bounds__(256, 6) void k_attn(
    const float* __restrict__ p, const int* __restrict__ idx,
    const float* __restrict__ xq, const uint_t* __restrict__ kvp,
    const float* __restrict__ Wp1, const float* __restrict__ bp1,
    const float* __restrict__ pg, const float* __restrict__ pb,
    const float* __restrict__ pm, const float* __restrict__ pv,
    const float* __restrict__ Wp2, const float* __restrict__ bp2,
    const float* __restrict__ wg1, const float* __restrict__ wb1,
    const float* __restrict__ wm1, const float* __restrict__ wv1,
    const float* __restrict__ Ww1, const float* __restrict__ bw1,
    const float* __restrict__ wg2, const float* __restrict__ wb2,
    const float* __restrict__ wm2, const float* __restrict__ wv2,
    const float* __restrict__ Ww2, const float* __restrict__ bw2,
    float* __restrict__ out)
{
    __shared__ float sw[4][16 * 68];   // per-wave wrel, stride 68 (b128-aligned)
    __shared__ float sh[4][16 * 9];    // per-wave h AND logits (merged, in-order DS)
    __shared__ float sW1[8 * 68];      // block-shared Ww1, stride 68

    const int tid   = threadIdx.x;
    const int wid   = __builtin_amdgcn_readfirstlane(tid >> 6);
    const int lane  = tid & 63;
    const int nbase = blockIdx.x * 16 + wid * 4;

    // stage Ww1 once per block
#pragma unroll
    for (int e = tid; e < 544; e += 256) {
        int r = e / 68, c = e - r * 68;
        sW1[e] = (c < 64) ? Ww1[r * 64 + c] : 0.f;
    }
    __syncthreads();

    float* wrel = sw[wid];
    float* hb   = sh[wid];

    const int* idxr = idx + (size_t)nbase * 16;     // wave-uniform base

    uint_t ga[16], gb[16];
    auto issueF = [&](int pt, uint_t (&dst)[16]) {
#pragma unroll
        for (int j = 0; j < 16; ++j) {
            int id = __builtin_amdgcn_readfirstlane(idxr[pt * 16 + j]);
            dst[j] = kvp[(size_t)id * 64 + lane];
        }
    };

    // ---- issue kv gathers for pts 0,1 FIRST (longest latency) ----
    issueF(0, ga);
    issueF(1, gb);

    // ---- strip loads: per-slot idx (vector), xq, p ----
    int   idv[4];
    float xqc[4];
#pragma unroll
    for (int pt = 0; pt < 4; ++pt) {
        idv[pt] = idxr[pt * 16 + (lane & 15)];
        xqc[pt] = xq[(size_t)(nbase + pt) * 64 + lane];
    }
    float gpx[4], gpy[4], gpz[4];
#pragma unroll
    for (int pt = 0; pt < 4; ++pt) {
        gpx[pt] = p[idv[pt] * 3 + 0];
        gpy[pt] = p[idv[pt] * 3 + 1];
        gpz[pt] = p[idv[pt] * 3 + 2];
    }

    // ---- tiny uniform params (linear_p folded BN) ----
    float w100 = Wp1[0], w101 = Wp1[1], w102 = Wp1[2];
    float w110 = Wp1[3], w111 = Wp1[4], w112 = Wp1[5];
    float w120 = Wp1[6], w121 = Wp1[7], w122 = Wp1[8];
    float sp0 = pg[0] * rsqrtf(pv[0] + EPSV);
    float sp1 = pg[1] * rsqrtf(pv[1] + EPSV);
    float sp2 = pg[2] * rsqrtf(pv[2] + EPSV);
    float off0 = (bp1[0] - pm[0]) * sp0 + pb[0];
    float off1 = (bp1[1] - pm[1]) * sp1 + pb[1];
    float off2 = (bp1[2] - pm[2]) * sp2 + pb[2];

    // ---- per-lane params ----
    float s1 = wg1[lane] * rsqrtf(wv1[lane] + EPSV);
    float o1 = wb1[lane] - wm1[lane] * s1;
    float wp2x = Wp2[lane * 3 + 0], wp2y = Wp2[lane * 3 + 1], wp2z = Wp2[lane * 3 + 2];
    float peb = bp2[lane];

    const int m  = lane & 7;
    const int j0 = lane >> 3;
    float s2 = wg2[m] * rsqrtf(wv2[m] + EPSV);
    float o2 = wb2[m] - wm2[m] * s2;
    float bw1v = bw1[m];
    float bw2v = bw2[m];
    float w2r[8];
#pragma unroll
    for (int mm = 0; mm < 8; ++mm) w2r[mm] = Ww2[m * 8 + mm];

    // ---- t-triples per point (slot = lane&15) ----
    float t0a[4], t1a[4], t2a[4];
#pragma unroll
    for (int pt = 0; pt < 4; ++pt) {
        int n = nbase + pt;
        float pcx = p[n * 3 + 0], pcy = p[n * 3 + 1], pcz = p[n * 3 + 2];
        float prx = gpx[pt] - pcx, pry = gpy[pt] - pcy, prz = gpz[pt] - pcz;
        t0a[pt] = fmaxf(fmaf(fmaf(prx, w100, fmaf(pry, w101, prz * w102)), sp0, off0), 0.f);
        t1a[pt] = fmaxf(fmaf(fmaf(prx, w110, fmaf(pry, w111, prz * w112)), sp1, off1), 0.f);
        t2a[pt] = fmaxf(fmaf(fmaf(prx, w120, fmaf(pry, w121, prz * w122)), sp2, off2), 0.f);
    }

    auto computeF = [&](int pt, uint_t (&g)[16]) {
        float t0v = t0a[pt], t1v = t1a[pt], t2v = t2a[pt];
        float xqv = xqc[pt];
        float vpe[16];
        // Phase A: pe + relation + bn1+relu -> wrel
#pragma unroll
        for (int j = 0; j < 16; ++j) {
            float tt0 = rdlane(t0v, j);
            float tt1 = rdlane(t1v, j);
            float tt2 = rdlane(t2v, j);
            float pe = fmaf(tt0, wp2x, fmaf(tt1, wp2y, fmaf(tt2, wp2z, peb)));
            float xkj = __uint_as_float(g[j] << 16);
            float xvj = __uint_as_float(g[j] & 0xffff0000u);
            vpe[j] = xvj + pe;
            wrel[j * 68 + lane] = fmaxf(fmaf(xkj - xqv + pe, s1, o1), 0.f);
        }
        asm volatile("s_waitcnt lgkmcnt(0)" ::: "memory");
        __builtin_amdgcn_wave_barrier();

        // Phase B1: w @ Ww1^T -> bn2+relu -> hb
#pragma unroll
        for (int pi = 0; pi < 2; ++pi) {
            int j = j0 + pi * 8;
            float acc = bw1v;
            const float* wr = wrel + j * 68;
#pragma unroll
            for (int c4 = 0; c4 < 16; ++c4) {
                float4 u = *((const float4*)(sW1 + m * 68 + c4 * 4));
                const float* r = wr + c4 * 4;
                acc = fmaf(r[0], u.x, fmaf(r[1], u.y, fmaf(r[2], u.z, fmaf(r[3], u.w, acc))));
            }
            hb[j * 9 + m] = fmaxf(fmaf(acc, s2, o2), 0.f);
        }
        asm volatile("s_waitcnt lgkmcnt(0)" ::: "memory");
        __builtin_amdgcn_wave_barrier();

        // Phase B2: @ Ww2^T -> logits (in-place into hb; wave-synchronous DS)
#pragma unroll
        for (int pi = 0; pi < 2; ++pi) {
            int j = j0 + pi * 8;
            float acc = bw2v;
#pragma unroll
            for (int mm = 0; mm < 8; ++mm) acc = fmaf(hb[j * 9 + mm], w2r[mm], acc);
            asm volatile("s_waitcnt lgkmcnt(0)" ::: "memory");
            __builtin_amdgcn_wave_barrier();
            hb[j * 9 + m] = acc;
        }
        asm volatile("s_waitcnt lgkmcnt(0)" ::: "memory");
        __builtin_amdgcn_wave_barrier();

        // Phase C: softmax over neighbors + weighted sum
        float mx = -1e30f;
        float e[16];
#pragma unroll
        for (int j = 0; j < 16; ++j) { e[j] = hb[j * 9 + m]; mx = fmaxf(mx, e[j]); }
        float ssum = 0.f;
#pragma unroll
        for (int j = 0; j < 16; ++j) { e[j] = __expf(e[j] - mx); ssum += e[j]; }
        float inv = 1.f / ssum;
        float acc = 0.f;
#pragma unroll
        for (int j = 0; j < 16; ++j) acc = fmaf(vpe[j], e[j], acc);
        asm volatile("s_waitcnt lgkmcnt(0)" ::: "memory");
        __builtin_amdgcn_wave_barrier();
        out[(size_t)(nbase + pt) * 64 + lane] = acc * inv;
    };

    // 2-deep pipelined strip
    computeF(0, ga);
    issueF(2, ga);
    computeF(1, gb);
    issueF(3, gb);
    computeF(2, ga);
    computeF(3, gb);
}

extern "C" void kernel_launch(void* const* d_in, const int* in_sizes, int n_in,
                              void* d_out, int out_size, void* d_ws, size_t ws_size,
                              hipStream_t stream) {
    const float* p   = (const float*)d_in[0];
    const float* x   = (const float*)d_in[1];
    const int*   idx = (const int*)d_in[2];
    const float* Wq  = (const float*)d_in[3];  const float* bq  = (const float*)d_in[4];
    const float* Wk  = (const float*)d_in[5];  const float* bk  = (const float*)d_in[6];
    const float* Wv  = (const float*)d_in[7];  const float* bv  = (const float*)d_in[8];
    const float* Wp1 = (const float*)d_in[9];  const float* bp1 = (const float*)d_in[10];
    const float* pg  = (const float*)d_in[11]; const float* pb  = (const float*)d_in[12];
    const float* pm  = (const float*)d_in[13]; const float* pv  = (const float*)d_in[14];
    const float* Wp2 = (const float*)d_in[15]; const float* bp2 = (const float*)d_in[16];
    const float* wg1 = (const float*)d_in[17]; const float* wb1 = (const float*)d_in[18];
    const float* wm1 = (const float*)d_in[19]; const float* wv1 = (const float*)d_in[20];
    const float* Ww1 = (const float*)d_in[21]; const float* bw1 = (const float*)d_in[22];
    const float* wg2 = (const float*)d_in[23]; const float* wb2 = (const float*)d_in[24];
    const float* wm2 = (const float*)d_in[25]; const float* wv2 = (const float*)d_in[26];
    const float* Ww2 = (const float*)d_in[27]; const float* bw2 = (const float*)d_in[28];

    float*  xqw = (float*)d_ws;
    uint_t* kvw = (uint_t*)((char*)d_ws + (size_t)NPTS * 64 * sizeof(float));
    float*  outp = (float*)d_out;

    k_qkv<<<dim3(NPTS / 64), dim3(256), 0, stream>>>(x, Wq, bq, Wk, bk, Wv, bv, xqw, kvw);
    k_attn<<<dim3(NPTS / 16), dim3(256), 0, stream>>>(p, idx, xqw, kvw,
                                                      Wp1, bp1, pg, pb, pm, pv, Wp2, bp2,
                                                      wg1, wb1, wm1, wv1, Ww1, bw1,
                                                      wg2, wb2, wm2, wv2, Ww2, bw2, outp);
}

// Round 6
// 211.386 us; speedup vs baseline: 4.6125x; 2.0115x over previous
//
#include <hip/hip_runtime.h>

#define NPTS 65536
#define EPSV 1e-5f

typedef unsigned int uint_t;
typedef unsigned short ushort_t;
typedef __attribute__((ext_vector_type(8))) short short8;
typedef __attribute__((ext_vector_type(4))) float float4v;

__device__ __forceinline__ ushort_t f2bf(float f) {
    unsigned u = __float_as_uint(f);
    unsigned r = (u + 0x7fffu + ((u >> 16) & 1u)) >> 16;
    return (ushort_t)r;
}

__device__ __forceinline__ float rdlane(float v, int j) {
    return __uint_as_float(__builtin_amdgcn_readlane(__float_as_uint(v), j));
}

// ---------------------------------------------------------------------------
// Kernel 1 (MFMA): C[64 x 192] = x_tile[64x64] @ [Wq;Wk;Wv]^T + bias
// Block = 256 thr / 4 waves, one 64-point M-chunk per block.
// x and W staged as bf16 in LDS (stride 72 shorts -> conflict-light b128).
// Wave w computes m-tile w (16 points) x all 12 n-tiles via 24 MFMAs.
// Epilogue: xq f32, kv packed bf16, written from C/D layout directly.
// ---------------------------------------------------------------------------
__global__ __launch_bounds__(256) void k_qkv(
    const float* __restrict__ x,
    const float* __restrict__ Wq, const float* __restrict__ bq,
    const float* __restrict__ Wk, const float* __restrict__ bk,
    const float* __restrict__ Wv, const float* __restrict__ bv,
    float* __restrict__ xq, uint_t* __restrict__ kvp)
{
    __shared__ __align__(16) ushort_t sA[64 * 72];    //  9 KB
    __shared__ __align__(16) ushort_t sB[192 * 72];   // 27 KB

    const int tid  = threadIdx.x;
    const int lane = tid & 63;
    const int w    = tid >> 6;
    const int n0   = blockIdx.x * 64;

    // ---- stage x tile (coalesced f32 -> bf16 LDS) ----
    const float4* xg = (const float4*)(x + (size_t)n0 * 64);
#pragma unroll
    for (int i = 0; i < 4; ++i) {
        int f = i * 256 + tid;
        float4 v = xg[f];
        int r = f >> 4, c4 = f & 15;
        uint2 pk;
        pk.x = (uint_t)f2bf(v.x) | ((uint_t)f2bf(v.y) << 16);
        pk.y = (uint_t)f2bf(v.z) | ((uint_t)f2bf(v.w) << 16);
        *(uint2*)(sA + r * 72 + c4 * 4) = pk;
    }
    // ---- stage Wq|Wk|Wv (rows 0-63 | 64-127 | 128-191) ----
#pragma unroll
    for (int i = 0; i < 12; ++i) {
        const float* src = (i < 4) ? Wq : (i < 8) ? Wk : Wv;
        int f = i * 256 + tid;                 // global float4 idx 0..3071
        int r = f >> 4, c4 = f & 15;
        float4 v = ((const float4*)src)[(i & 3) * 256 + tid];
        uint2 pk;
        pk.x = (uint_t)f2bf(v.x) | ((uint_t)f2bf(v.y) << 16);
        pk.y = (uint_t)f2bf(v.z) | ((uint_t)f2bf(v.w) << 16);
        *(uint2*)(sB + r * 72 + c4 * 4) = pk;
    }
    __syncthreads();

    // ---- MFMA: wave w -> rows [16w,16w+16), 12 n-tiles, K=64 (2 steps) ----
    const int quad = lane >> 4;
    const int cn   = lane & 15;
    const int mrow = (w << 4) + cn;

    short8 a0 = *(const short8*)(sA + mrow * 72 + quad * 8);
    short8 a1 = *(const short8*)(sA + mrow * 72 + 32 + quad * 8);

    float4v acc[12];
#pragma unroll
    for (int t = 0; t < 12; ++t) {
        const int brow = t * 16 + cn;
        short8 b0 = *(const short8*)(sB + brow * 72 + quad * 8);
        short8 b1 = *(const short8*)(sB + brow * 72 + 32 + quad * 8);
        float4v c = {0.f, 0.f, 0.f, 0.f};
        c = __builtin_amdgcn_mfma_f32_16x16x32_bf16(a0, b0, c, 0, 0, 0);
        c = __builtin_amdgcn_mfma_f32_16x16x32_bf16(a1, b1, c, 0, 0, 0);
        acc[t] = c;
    }

    // ---- epilogue: C/D layout col=lane&15, row=quad*4+reg ----
    const int orow = n0 + (w << 4) + quad * 4;
#pragma unroll
    for (int t = 0; t < 4; ++t) {
        int o = t * 16 + cn;
        float bqv = bq[o], bkv = bk[o], bvv = bv[o];
        float4v aq = acc[t], ak = acc[4 + t], av = acc[8 + t];
#pragma unroll
        for (int r = 0; r < 4; ++r) {
            size_t base = (size_t)(orow + r) * 64 + o;
            xq[base]  = aq[r] + bqv;
            kvp[base] = (uint_t)f2bf(ak[r] + bkv) | ((uint_t)f2bf(av[r] + bvv) << 16);
        }
    }
}

// ---------------------------------------------------------------------------
// Kernel 2: one wave per 4-point strip; barrier-free after Ww1 staging;
// kv gathers issued first; Ww1 in block LDS; stride-68 b128.
// launch_bounds(256,4): 128-VGPR budget -> NO scratch spill (round-5 lesson).
// ---------------------------------------------------------------------------
__global__ __launch_bounds__(256, 4) void k_attn(
    const float* __restrict__ p, const int* __restrict__ idx,
    const float* __restrict__ xq, const uint_t* __restrict__ kvp,
    const float* __restrict__ Wp1, const float* __restrict__ bp1,
    const float* __restrict__ pg, const float* __restrict__ pb,
    const float* __restrict__ pm, const float* __restrict__ pv,
    const float* __restrict__ Wp2, const float* __restrict__ bp2,
    const float* __restrict__ wg1, const float* __restrict__ wb1,
    const float* __restrict__ wm1, const float* __restrict__ wv1,
    const float* __restrict__ Ww1, const float* __restrict__ bw1,
    const float* __restrict__ wg2, const float* __restrict__ wb2,
    const float* __restrict__ wm2, const float* __restrict__ wv2,
    const float* __restrict__ Ww2, const float* __restrict__ bw2,
    float* __restrict__ out)
{
    __shared__ float sw[4][16 * 68];   // per-wave wrel, stride 68 (b128-aligned)
    __shared__ float sh[4][16 * 9];    // per-wave h AND logits (merged, in-order DS)
    __shared__ float sW1[8 * 68];      // block-shared Ww1, stride 68

    const int tid   = threadIdx.x;
    const int wid   = __builtin_amdgcn_readfirstlane(tid >> 6);
    const int lane  = tid & 63;
    const int nbase = blockIdx.x * 16 + wid * 4;

    // stage Ww1 once per block
#pragma unroll
    for (int e = tid; e < 544; e += 256) {
        int r = e / 68, c = e - r * 68;
        sW1[e] = (c < 64) ? Ww1[r * 64 + c] : 0.f;
    }
    __syncthreads();

    float* wrel = sw[wid];
    float* hb   = sh[wid];

    const int* idxr = idx + (size_t)nbase * 16;     // wave-uniform base

    uint_t ga[16], gb[16];
    auto issueF = [&](int pt, uint_t (&dst)[16]) {
#pragma unroll
        for (int j = 0; j < 16; ++j) {
            int id = __builtin_amdgcn_readfirstlane(idxr[pt * 16 + j]);
            dst[j] = kvp[(size_t)id * 64 + lane];
        }
    };

    // ---- issue kv gathers for pts 0,1 FIRST (longest latency) ----
    issueF(0, ga);
    issueF(1, gb);

    // ---- strip loads: per-slot idx (vector), xq, p ----
    int   idv[4];
    float xqc[4];
#pragma unroll
    for (int pt = 0; pt < 4; ++pt) {
        idv[pt] = idxr[pt * 16 + (lane & 15)];
        xqc[pt] = xq[(size_t)(nbase + pt) * 64 + lane];
    }
    float gpx[4], gpy[4], gpz[4];
#pragma unroll
    for (int pt = 0; pt < 4; ++pt) {
        gpx[pt] = p[idv[pt] * 3 + 0];
        gpy[pt] = p[idv[pt] * 3 + 1];
        gpz[pt] = p[idv[pt] * 3 + 2];
    }

    // ---- tiny uniform params (linear_p folded BN) ----
    float w100 = Wp1[0], w101 = Wp1[1], w102 = Wp1[2];
    float w110 = Wp1[3], w111 = Wp1[4], w112 = Wp1[5];
    float w120 = Wp1[6], w121 = Wp1[7], w122 = Wp1[8];
    float sp0 = pg[0] * rsqrtf(pv[0] + EPSV);
    float sp1 = pg[1] * rsqrtf(pv[1] + EPSV);
    float sp2 = pg[2] * rsqrtf(pv[2] + EPSV);
    float off0 = (bp1[0] - pm[0]) * sp0 + pb[0];
    float off1 = (bp1[1] - pm[1]) * sp1 + pb[1];
    float off2 = (bp1[2] - pm[2]) * sp2 + pb[2];

    // ---- per-lane params ----
    float s1 = wg1[lane] * rsqrtf(wv1[lane] + EPSV);
    float o1 = wb1[lane] - wm1[lane] * s1;
    float wp2x = Wp2[lane * 3 + 0], wp2y = Wp2[lane * 3 + 1], wp2z = Wp2[lane * 3 + 2];
    float peb = bp2[lane];

    const int m  = lane & 7;
    const int j0 = lane >> 3;
    float s2 = wg2[m] * rsqrtf(wv2[m] + EPSV);
    float o2 = wb2[m] - wm2[m] * s2;
    float bw1v = bw1[m];
    float bw2v = bw2[m];
    float w2r[8];
#pragma unroll
    for (int mm = 0; mm < 8; ++mm) w2r[mm] = Ww2[m * 8 + mm];

    // ---- t-triples per point (slot = lane&15) ----
    float t0a[4], t1a[4], t2a[4];
#pragma unroll
    for (int pt = 0; pt < 4; ++pt) {
        int n = nbase + pt;
        float pcx = p[n * 3 + 0], pcy = p[n * 3 + 1], pcz = p[n * 3 + 2];
        float prx = gpx[pt] - pcx, pry = gpy[pt] - pcy, prz = gpz[pt] - pcz;
        t0a[pt] = fmaxf(fmaf(fmaf(prx, w100, fmaf(pry, w101, prz * w102)), sp0, off0), 0.f);
        t1a[pt] = fmaxf(fmaf(fmaf(prx, w110, fmaf(pry, w111, prz * w112)), sp1, off1), 0.f);
        t2a[pt] = fmaxf(fmaf(fmaf(prx, w120, fmaf(pry, w121, prz * w122)), sp2, off2), 0.f);
    }

    auto computeF = [&](int pt, uint_t (&g)[16]) {
        float t0v = t0a[pt], t1v = t1a[pt], t2v = t2a[pt];
        float xqv = xqc[pt];
        float vpe[16];
        // Phase A: pe + relation + bn1+relu -> wrel
#pragma unroll
        for (int j = 0; j < 16; ++j) {
            float tt0 = rdlane(t0v, j);
            float tt1 = rdlane(t1v, j);
            float tt2 = rdlane(t2v, j);
            float pe = fmaf(tt0, wp2x, fmaf(tt1, wp2y, fmaf(tt2, wp2z, peb)));
            float xkj = __uint_as_float(g[j] << 16);
            float xvj = __uint_as_float(g[j] & 0xffff0000u);
            vpe[j] = xvj + pe;
            wrel[j * 68 + lane] = fmaxf(fmaf(xkj - xqv + pe, s1, o1), 0.f);
        }
        asm volatile("s_waitcnt lgkmcnt(0)" ::: "memory");
        __builtin_amdgcn_wave_barrier();

        // Phase B1: w @ Ww1^T -> bn2+relu -> hb
#pragma unroll
        for (int pi = 0; pi < 2; ++pi) {
            int j = j0 + pi * 8;
            float acc = bw1v;
            const float* wr = wrel + j * 68;
#pragma unroll
            for (int c4 = 0; c4 < 16; ++c4) {
                float4 u = *((const float4*)(sW1 + m * 68 + c4 * 4));
                const float* r = wr + c4 * 4;
                acc = fmaf(r[0], u.x, fmaf(r[1], u.y, fmaf(r[2], u.z, fmaf(r[3], u.w, acc))));
            }
            hb[j * 9 + m] = fmaxf(fmaf(acc, s2, o2), 0.f);
        }
        asm volatile("s_waitcnt lgkmcnt(0)" ::: "memory");
        __builtin_amdgcn_wave_barrier();

        // Phase B2: @ Ww2^T -> logits (in-place into hb; wave-synchronous DS)
#pragma unroll
        for (int pi = 0; pi < 2; ++pi) {
            int j = j0 + pi * 8;
            float acc = bw2v;
#pragma unroll
            for (int mm = 0; mm < 8; ++mm) acc = fmaf(hb[j * 9 + mm], w2r[mm], acc);
            asm volatile("s_waitcnt lgkmcnt(0)" ::: "memory");
            __builtin_amdgcn_wave_barrier();
            hb[j * 9 + m] = acc;
        }
        asm volatile("s_waitcnt lgkmcnt(0)" ::: "memory");
        __builtin_amdgcn_wave_barrier();

        // Phase C: softmax over neighbors + weighted sum
        float mx = -1e30f;
        float e[16];
#pragma unroll
        for (int j = 0; j < 16; ++j) { e[j] = hb[j * 9 + m]; mx = fmaxf(mx, e[j]); }
        float ssum = 0.f;
#pragma unroll
        for (int j = 0; j < 16; ++j) { e[j] = __expf(e[j] - mx); ssum += e[j]; }
        float inv = 1.f / ssum;
        float acc = 0.f;
#pragma unroll
        for (int j = 0; j < 16; ++j) acc = fmaf(vpe[j], e[j], acc);
        asm volatile("s_waitcnt lgkmcnt(0)" ::: "memory");
        __builtin_amdgcn_wave_barrier();
        out[(size_t)(nbase + pt) * 64 + lane] = acc * inv;
    };

    // 2-deep pipelined strip
    computeF(0, ga);
    issueF(2, ga);
    computeF(1, gb);
    issueF(3, gb);
    computeF(2, ga);
    computeF(3, gb);
}

extern "C" void kernel_launch(void* const* d_in, const int* in_sizes, int n_in,
                              void* d_out, int out_size, void* d_ws, size_t ws_size,
                              hipStream_t stream) {
    const float* p   = (const float*)d_in[0];
    const float* x   = (const float*)d_in[1];
    const int*   idx = (const int*)d_in[2];
    const float* Wq  = (const float*)d_in[3];  const float* bq  = (const float*)d_in[4];
    const float* Wk  = (const float*)d_in[5];  const float* bk  = (const float*)d_in[6];
    const float* Wv  = (const float*)d_in[7];  const float* bv  = (const float*)d_in[8];
    const float* Wp1 = (const float*)d_in[9];  const float* bp1 = (const float*)d_in[10];
    const float* pg  = (const float*)d_in[11]; const float* pb  = (const float*)d_in[12];
    const float* pm  = (const float*)d_in[13]; const float* pv  = (const float*)d_in[14];
    const float* Wp2 = (const float*)d_in[15]; const float* bp2 = (const float*)d_in[16];
    const float* wg1 = (const float*)d_in[17]; const float* wb1 = (const float*)d_in[18];
    const float* wm1 = (const float*)d_in[19]; const float* wv1 = (const float*)d_in[20];
    const float* Ww1 = (const float*)d_in[21]; const float* bw1 = (const float*)d_in[22];
    const float* wg2 = (const float*)d_in[23]; const float* wb2 = (const float*)d_in[24];
    const float* wm2 = (const float*)d_in[25]; const float* wv2 = (const float*)d_in[26];
    const float* Ww2 = (const float*)d_in[27]; const float* bw2 = (const float*)d_in[28];

    float*  xqw = (float*)d_ws;
    uint_t* kvw = (uint_t*)((char*)d_ws + (size_t)NPTS * 64 * sizeof(float));
    float*  outp = (float*)d_out;

    k_qkv<<<dim3(NPTS / 64), dim3(256), 0, stream>>>(x, Wq, bq, Wk, bk, Wv, bv, xqw, kvw);
    k_attn<<<dim3(NPTS / 16), dim3(256), 0, stream>>>(p, idx, xqw, kvw,
                                                      Wp1, bp1, pg, pb, pm, pv, Wp2, bp2,
                                                      wg1, wb1, wm1, wv1, Ww1, bw1,
                                                      wg2, wb2, wm2, wv2, Ww2, bw2, outp);
}

// Round 7
// 190.355 us; speedup vs baseline: 5.1221x; 1.1105x over previous
//
#include <hip/hip_runtime.h>

#define NPTS 65536
#define EPSV 1e-5f

typedef unsigned int uint_t;
typedef unsigned short ushort_t;
typedef __attribute__((ext_vector_type(8))) short short8;
typedef __attribute__((ext_vector_type(4))) float float4v;

union U8 { uint4 u; short8 s; };

__device__ __forceinline__ ushort_t f2bf(float f) {
    unsigned u = __float_as_uint(f);
    unsigned r = (u + 0x7fffu + ((u >> 16) & 1u)) >> 16;
    return (ushort_t)r;
}

__device__ __forceinline__ uint_t pkrn(uint_t lo, uint_t hi) {
    return ((lo + 0x8000u) >> 16) | ((hi + 0x8000u) & 0xffff0000u);
}

// 8 consecutive f32 (LDS, 16B-aligned) -> bf16x8 fragment
__device__ __forceinline__ short8 packA(const float* p8) {
    uint4 a = *(const uint4*)p8;
    uint4 b = *(const uint4*)(p8 + 4);
    U8 c;
    c.u.x = pkrn(a.x, a.y); c.u.y = pkrn(a.z, a.w);
    c.u.z = pkrn(b.x, b.y); c.u.w = pkrn(b.z, b.w);
    return c.s;
}

// 8 consecutive f32 (global) -> bf16x8 fragment
__device__ __forceinline__ short8 packG(const float* p8) {
    float4 a = *(const float4*)p8;
    float4 b = *(const float4*)(p8 + 4);
    U8 c;
    c.u.x = pkrn(__float_as_uint(a.x), __float_as_uint(a.y));
    c.u.y = pkrn(__float_as_uint(a.z), __float_as_uint(a.w));
    c.u.z = pkrn(__float_as_uint(b.x), __float_as_uint(b.y));
    c.u.w = pkrn(__float_as_uint(b.z), __float_as_uint(b.w));
    return c.s;
}

#define WBAR() do { asm volatile("s_waitcnt lgkmcnt(0)" ::: "memory"); \
                    __builtin_amdgcn_wave_barrier(); } while (0)

// ---------------------------------------------------------------------------
// Kernel 1 (MFMA): C[64 x 192] = x_tile[64x64] @ [Wq;Wk;Wv]^T + bias
// (unchanged from round 6 — ~5 us)
// ---------------------------------------------------------------------------
__global__ __launch_bounds__(256) void k_qkv(
    const float* __restrict__ x,
    const float* __restrict__ Wq, const float* __restrict__ bq,
    const float* __restrict__ Wk, const float* __restrict__ bk,
    const float* __restrict__ Wv, const float* __restrict__ bv,
    float* __restrict__ xq, uint_t* __restrict__ kvp)
{
    __shared__ __align__(16) ushort_t sA[64 * 72];
    __shared__ __align__(16) ushort_t sB[192 * 72];

    const int tid  = threadIdx.x;
    const int lane = tid & 63;
    const int w    = tid >> 6;
    const int n0   = blockIdx.x * 64;

    const float4* xg = (const float4*)(x + (size_t)n0 * 64);
#pragma unroll
    for (int i = 0; i < 4; ++i) {
        int f = i * 256 + tid;
        float4 v = xg[f];
        int r = f >> 4, c4 = f & 15;
        uint2 pk;
        pk.x = (uint_t)f2bf(v.x) | ((uint_t)f2bf(v.y) << 16);
        pk.y = (uint_t)f2bf(v.z) | ((uint_t)f2bf(v.w) << 16);
        *(uint2*)(sA + r * 72 + c4 * 4) = pk;
    }
#pragma unroll
    for (int i = 0; i < 12; ++i) {
        const float* src = (i < 4) ? Wq : (i < 8) ? Wk : Wv;
        int f = i * 256 + tid;
        int r = f >> 4, c4 = f & 15;
        float4 v = ((const float4*)src)[(i & 3) * 256 + tid];
        uint2 pk;
        pk.x = (uint_t)f2bf(v.x) | ((uint_t)f2bf(v.y) << 16);
        pk.y = (uint_t)f2bf(v.z) | ((uint_t)f2bf(v.w) << 16);
        *(uint2*)(sB + r * 72 + c4 * 4) = pk;
    }
    __syncthreads();

    const int quad = lane >> 4;
    const int cn   = lane & 15;
    const int mrow = (w << 4) + cn;

    short8 a0 = *(const short8*)(sA + mrow * 72 + quad * 8);
    short8 a1 = *(const short8*)(sA + mrow * 72 + 32 + quad * 8);

    float4v acc[12];
#pragma unroll
    for (int t = 0; t < 12; ++t) {
        const int brow = t * 16 + cn;
        short8 b0 = *(const short8*)(sB + brow * 72 + quad * 8);
        short8 b1 = *(const short8*)(sB + brow * 72 + 32 + quad * 8);
        float4v c = {0.f, 0.f, 0.f, 0.f};
        c = __builtin_amdgcn_mfma_f32_16x16x32_bf16(a0, b0, c, 0, 0, 0);
        c = __builtin_amdgcn_mfma_f32_16x16x32_bf16(a1, b1, c, 0, 0, 0);
        acc[t] = c;
    }

    const int orow = n0 + (w << 4) + quad * 4;
#pragma unroll
    for (int t = 0; t < 4; ++t) {
        int o = t * 16 + cn;
        float bqv = bq[o], bkv = bk[o], bvv = bv[o];
        float4v aq = acc[t], ak = acc[4 + t], av = acc[8 + t];
#pragma unroll
        for (int r = 0; r < 4; ++r) {
            size_t base = (size_t)(orow + r) * 64 + o;
            xq[base]  = aq[r] + bqv;
            kvp[base] = (uint_t)f2bf(ak[r] + bkv) | ((uint_t)f2bf(av[r] + bvv) << 16);
        }
    }
}

// ---------------------------------------------------------------------------
// Kernel 2: one wave per 4-point strip; relation MLP via MFMA; barrier-free;
// 2-deep pipelined gathers. launch_bounds(256,3): 170-VGPR budget, no spill.
// ---------------------------------------------------------------------------
__global__ __launch_bounds__(256, 3) void k_attn(
    const float* __restrict__ p, const int* __restrict__ idx,
    const float* __restrict__ xq, const uint_t* __restrict__ kvp,
    const float* __restrict__ Wp1, const float* __restrict__ bp1,
    const float* __restrict__ pg, const float* __restrict__ pb,
    const float* __restrict__ pm, const float* __restrict__ pv,
    const float* __restrict__ Wp2, const float* __restrict__ bp2,
    const float* __restrict__ wg1, const float* __restrict__ wb1,
    const float* __restrict__ wm1, const float* __restrict__ wv1,
    const float* __restrict__ Ww1, const float* __restrict__ bw1,
    const float* __restrict__ wg2, const float* __restrict__ wb2,
    const float* __restrict__ wm2, const float* __restrict__ wv2,
    const float* __restrict__ Ww2, const float* __restrict__ bw2,
    float* __restrict__ out)
{
    __shared__ __align__(16) float sw[4][16 * 68];   // per-wave wrel (f32)
    __shared__ __align__(16) float shl[4][16 * 36];  // per-wave h, K-padded with zeros
    __shared__ float swg[4][16 * 9 + 4];             // per-wave attention weights

    const int tid   = threadIdx.x;
    const int wid   = __builtin_amdgcn_readfirstlane(tid >> 6);
    const int lane  = tid & 63;
    const int nbase = blockIdx.x * 16 + wid * 4;

    float* wrel = sw[wid];
    float* hL   = shl[wid];
    float* wgt  = swg[wid];

    const int cm  = lane & 15;     // MFMA col / j-row index
    const int q   = lane >> 4;     // quad
    const int m8  = lane & 7;      // share-plane for output channel
    const int cmc = cm & 7;
    const bool colv = cm < 8;

    const int* idxr = idx + (size_t)nbase * 16;     // wave-uniform base

    uint_t ga[16], gb[16];
    auto issueF = [&](int pt, uint_t (&dst)[16]) {
#pragma unroll
        for (int j = 0; j < 16; ++j) {
            int id = __builtin_amdgcn_readfirstlane(idxr[pt * 16 + j]);
            dst[j] = kvp[(size_t)id * 64 + lane];
        }
    };

    // ---- issue kv gathers for pts 0,1 FIRST ----
    issueF(0, ga);
    issueF(1, gb);

    // ---- zero-fill h K-pad region (cols 8..31 stay 0 forever) ----
    for (int i = lane; i < 16 * 36; i += 64) hL[i] = 0.f;

    // ---- strip loads ----
    int   idv[4];
    float xqc[4];
#pragma unroll
    for (int pt = 0; pt < 4; ++pt) {
        idv[pt] = idxr[pt * 16 + cm];
        xqc[pt] = xq[(size_t)(nbase + pt) * 64 + lane];
    }
    float gpx[4], gpy[4], gpz[4];
#pragma unroll
    for (int pt = 0; pt < 4; ++pt) {
        gpx[pt] = p[idv[pt] * 3 + 0];
        gpy[pt] = p[idv[pt] * 3 + 1];
        gpz[pt] = p[idv[pt] * 3 + 2];
    }

    // ---- tiny uniform params (linear_p folded BN) ----
    float w100 = Wp1[0], w101 = Wp1[1], w102 = Wp1[2];
    float w110 = Wp1[3], w111 = Wp1[4], w112 = Wp1[5];
    float w120 = Wp1[6], w121 = Wp1[7], w122 = Wp1[8];
    float sp0 = pg[0] * rsqrtf(pv[0] + EPSV);
    float sp1 = pg[1] * rsqrtf(pv[1] + EPSV);
    float sp2 = pg[2] * rsqrtf(pv[2] + EPSV);
    float off0 = (bp1[0] - pm[0]) * sp0 + pb[0];
    float off1 = (bp1[1] - pm[1]) * sp1 + pb[1];
    float off2 = (bp1[2] - pm[2]) * sp2 + pb[2];

    // ---- per-lane params ----
    float s1 = wg1[lane] * rsqrtf(wv1[lane] + EPSV);
    float o1 = wb1[lane] - wm1[lane] * s1;
    float wp2x = Wp2[lane * 3 + 0], wp2y = Wp2[lane * 3 + 1], wp2z = Wp2[lane * 3 + 2];
    float peb = bp2[lane];

    // col params for bn2 (col = cm, valid < 8)
    float s2c = wg2[cmc] * rsqrtf(wv2[cmc] + EPSV);
    float o2c = wb2[cmc] - wm2[cmc] * s2c;
    float bw1c = bw1[cmc];

    // ---- MFMA B-fragments (held in registers for whole kernel) ----
    short8 bf1a, bf1b, bf2;
    {
        const float* r1 = Ww1 + cmc * 64 + q * 8;
        short8 t1a = packG(r1);
        short8 t1b = packG(r1 + 32);
        short8 t2  = packG(Ww2 + cmc * 8);
        U8 z; z.u = make_uint4(0u, 0u, 0u, 0u);
        bf1a = colv ? t1a : z.s;
        bf1b = colv ? t1b : z.s;
        bf2  = (colv && q == 0) ? t2 : z.s;
    }

    // ---- t-triples per point (slot = cm) ----
    float t0a[4], t1a[4], t2a[4];
#pragma unroll
    for (int pt = 0; pt < 4; ++pt) {
        int n = nbase + pt;
        float pcx = p[n * 3 + 0], pcy = p[n * 3 + 1], pcz = p[n * 3 + 2];
        float prx = gpx[pt] - pcx, pry = gpy[pt] - pcy, prz = gpz[pt] - pcz;
        t0a[pt] = fmaxf(fmaf(fmaf(prx, w100, fmaf(pry, w101, prz * w102)), sp0, off0), 0.f);
        t1a[pt] = fmaxf(fmaf(fmaf(prx, w110, fmaf(pry, w111, prz * w112)), sp1, off1), 0.f);
        t2a[pt] = fmaxf(fmaf(fmaf(prx, w120, fmaf(pry, w121, prz * w122)), sp2, off2), 0.f);
    }

    auto computeF = [&](int pt, uint_t (&g)[16]) {
        float t0v = t0a[pt], t1v = t1a[pt], t2v = t2a[pt];
        float xqv = xqc[pt];
        float vpe[16];
        // ---- Phase A: pe + relation + bn1+relu -> wrel (f32) ----
#pragma unroll
        for (int j = 0; j < 16; ++j) {
            float tt0 = __uint_as_float(__builtin_amdgcn_readlane(__float_as_uint(t0v), j));
            float tt1 = __uint_as_float(__builtin_amdgcn_readlane(__float_as_uint(t1v), j));
            float tt2 = __uint_as_float(__builtin_amdgcn_readlane(__float_as_uint(t2v), j));
            float pe = fmaf(tt0, wp2x, fmaf(tt1, wp2y, fmaf(tt2, wp2z, peb)));
            float xkj = __uint_as_float(g[j] << 16);
            float xvj = __uint_as_float(g[j] & 0xffff0000u);
            vpe[j] = xvj + pe;
            wrel[j * 68 + lane] = fmaxf(fmaf(xkj - xqv + pe, s1, o1), 0.f);
        }
        WBAR();

        // ---- Phase B1 (MFMA): wrel[16x64] @ Ww1^T -> D1, bn2+relu -> hL ----
        short8 a1a = packA(wrel + cm * 68 + q * 8);
        short8 a1b = packA(wrel + cm * 68 + 32 + q * 8);
        float4v d1 = {0.f, 0.f, 0.f, 0.f};
        d1 = __builtin_amdgcn_mfma_f32_16x16x32_bf16(a1a, bf1a, d1, 0, 0, 0);
        d1 = __builtin_amdgcn_mfma_f32_16x16x32_bf16(a1b, bf1b, d1, 0, 0, 0);
#pragma unroll
        for (int r = 0; r < 4; ++r) {
            float hv = fmaxf(fmaf(d1[r] + bw1c, s2c, o2c), 0.f);
            if (colv) hL[(q * 4 + r) * 36 + cm] = hv;
        }
        WBAR();

        // ---- Phase B2 (MFMA, K=8 zero-padded): h @ Ww2^T -> logits ----
        short8 a2 = packA(hL + cm * 36 + q * 8);
        float4v d2 = {0.f, 0.f, 0.f, 0.f};
        d2 = __builtin_amdgcn_mfma_f32_16x16x32_bf16(a2, bf2, d2, 0, 0, 0);
        // (bw2 is constant over the softmax axis j -> cancels; skipped)

        // ---- Phase C: softmax over j (each lane holds 4 j's at col cm) ----
        float mx = fmaxf(fmaxf(d2[0], d2[1]), fmaxf(d2[2], d2[3]));
        mx = fmaxf(mx, __shfl_xor(mx, 16));
        mx = fmaxf(mx, __shfl_xor(mx, 32));
        float e0 = __expf(d2[0] - mx), e1 = __expf(d2[1] - mx);
        float e2 = __expf(d2[2] - mx), e3 = __expf(d2[3] - mx);
        float ss = e0 + e1 + e2 + e3;
        ss += __shfl_xor(ss, 16);
        ss += __shfl_xor(ss, 32);
        float inv = 1.f / ss;
        if (colv) {
            wgt[(q * 4 + 0) * 9 + cm] = e0 * inv;
            wgt[(q * 4 + 1) * 9 + cm] = e1 * inv;
            wgt[(q * 4 + 2) * 9 + cm] = e2 * inv;
            wgt[(q * 4 + 3) * 9 + cm] = e3 * inv;
        }
        WBAR();

        // ---- weighted sum over neighbors ----
        float acc = 0.f;
#pragma unroll
        for (int j = 0; j < 16; ++j) acc = fmaf(wgt[j * 9 + m8], vpe[j], acc);
        WBAR();
        out[(size_t)(nbase + pt) * 64 + lane] = acc;
    };

    // 2-deep pipelined strip
    computeF(0, ga);
    issueF(2, ga);
    computeF(1, gb);
    issueF(3, gb);
    computeF(2, ga);
    computeF(3, gb);
}

extern "C" void kernel_launch(void* const* d_in, const int* in_sizes, int n_in,
                              void* d_out, int out_size, void* d_ws, size_t ws_size,
                              hipStream_t stream) {
    const float* p   = (const float*)d_in[0];
    const float* x   = (const float*)d_in[1];
    const int*   idx = (const int*)d_in[2];
    const float* Wq  = (const float*)d_in[3];  const float* bq  = (const float*)d_in[4];
    const float* Wk  = (const float*)d_in[5];  const float* bk  = (const float*)d_in[6];
    const float* Wv  = (const float*)d_in[7];  const float* bv  = (const float*)d_in[8];
    const float* Wp1 = (const float*)d_in[9];  const float* bp1 = (const float*)d_in[10];
    const float* pg  = (const float*)d_in[11]; const float* pb  = (const float*)d_in[12];
    const float* pm  = (const float*)d_in[13]; const float* pv  = (const float*)d_in[14];
    const float* Wp2 = (const float*)d_in[15]; const float* bp2 = (const float*)d_in[16];
    const float* wg1 = (const float*)d_in[17]; const float* wb1 = (const float*)d_in[18];
    const float* wm1 = (const float*)d_in[19]; const float* wv1 = (const float*)d_in[20];
    const float* Ww1 = (const float*)d_in[21]; const float* bw1 = (const float*)d_in[22];
    const float* wg2 = (const float*)d_in[23]; const float* wb2 = (const float*)d_in[24];
    const float* wm2 = (const float*)d_in[25]; const float* wv2 = (const float*)d_in[26];
    const float* Ww2 = (const float*)d_in[27]; const float* bw2 = (const float*)d_in[28];

    float*  xqw = (float*)d_ws;
    uint_t* kvw = (uint_t*)((char*)d_ws + (size_t)NPTS * 64 * sizeof(float));
    float*  outp = (float*)d_out;

    k_qkv<<<dim3(NPTS / 64), dim3(256), 0, stream>>>(x, Wq, bq, Wk, bk, Wv, bv, xqw, kvw);
    k_attn<<<dim3(NPTS / 16), dim3(256), 0, stream>>>(p, idx, xqw, kvw,
                                                      Wp1, bp1, pg, pb, pm, pv, Wp2, bp2,
                                                      wg1, wb1, wm1, wv1, Ww1, bw1,
                                                      wg2, wb2, wm2, wv2, Ww2, bw2, outp);
}

// Round 8
// 184.670 us; speedup vs baseline: 5.2798x; 1.0308x over previous
//
#include <hip/hip_runtime.h>

#define NPTS 65536
#define EPSV 1e-5f

typedef unsigned int uint_t;
typedef unsigned short ushort_t;
typedef __attribute__((ext_vector_type(8))) short short8;
typedef __attribute__((ext_vector_type(4))) float float4v;

union U8 { uint4 u; short8 s; };

__device__ __forceinline__ ushort_t f2bf(float f) {
    unsigned u = __float_as_uint(f);
    unsigned r = (u + 0x7fffu + ((u >> 16) & 1u)) >> 16;
    return (ushort_t)r;
}

__device__ __forceinline__ uint_t pkrn(uint_t lo, uint_t hi) {
    return ((lo + 0x8000u) >> 16) | ((hi + 0x8000u) & 0xffff0000u);
}

// 8 consecutive f32 (global) -> bf16x8 fragment
__device__ __forceinline__ short8 packG(const float* p8) {
    float4 a = *(const float4*)p8;
    float4 b = *(const float4*)(p8 + 4);
    U8 c;
    c.u.x = pkrn(__float_as_uint(a.x), __float_as_uint(a.y));
    c.u.y = pkrn(__float_as_uint(a.z), __float_as_uint(a.w));
    c.u.z = pkrn(__float_as_uint(b.x), __float_as_uint(b.y));
    c.u.w = pkrn(__float_as_uint(b.z), __float_as_uint(b.w));
    return c.s;
}

#define WBAR() do { asm volatile("s_waitcnt lgkmcnt(0)" ::: "memory"); \
                    __builtin_amdgcn_wave_barrier(); } while (0)

// ---------------------------------------------------------------------------
// Kernel 1 (MFMA): C[64 x 192] = x_tile[64x64] @ [Wq;Wk;Wv]^T + bias
// (unchanged — ~5 us)
// ---------------------------------------------------------------------------
__global__ __launch_bounds__(256) void k_qkv(
    const float* __restrict__ x,
    const float* __restrict__ Wq, const float* __restrict__ bq,
    const float* __restrict__ Wk, const float* __restrict__ bk,
    const float* __restrict__ Wv, const float* __restrict__ bv,
    float* __restrict__ xq, uint_t* __restrict__ kvp)
{
    __shared__ __align__(16) ushort_t sA[64 * 72];
    __shared__ __align__(16) ushort_t sB[192 * 72];

    const int tid  = threadIdx.x;
    const int lane = tid & 63;
    const int w    = tid >> 6;
    const int n0   = blockIdx.x * 64;

    const float4* xg = (const float4*)(x + (size_t)n0 * 64);
#pragma unroll
    for (int i = 0; i < 4; ++i) {
        int f = i * 256 + tid;
        float4 v = xg[f];
        int r = f >> 4, c4 = f & 15;
        uint2 pk;
        pk.x = (uint_t)f2bf(v.x) | ((uint_t)f2bf(v.y) << 16);
        pk.y = (uint_t)f2bf(v.z) | ((uint_t)f2bf(v.w) << 16);
        *(uint2*)(sA + r * 72 + c4 * 4) = pk;
    }
#pragma unroll
    for (int i = 0; i < 12; ++i) {
        const float* src = (i < 4) ? Wq : (i < 8) ? Wk : Wv;
        int f = i * 256 + tid;
        int r = f >> 4, c4 = f & 15;
        float4 v = ((const float4*)src)[(i & 3) * 256 + tid];
        uint2 pk;
        pk.x = (uint_t)f2bf(v.x) | ((uint_t)f2bf(v.y) << 16);
        pk.y = (uint_t)f2bf(v.z) | ((uint_t)f2bf(v.w) << 16);
        *(uint2*)(sB + r * 72 + c4 * 4) = pk;
    }
    __syncthreads();

    const int quad = lane >> 4;
    const int cn   = lane & 15;
    const int mrow = (w << 4) + cn;

    short8 a0 = *(const short8*)(sA + mrow * 72 + quad * 8);
    short8 a1 = *(const short8*)(sA + mrow * 72 + 32 + quad * 8);

    float4v acc[12];
#pragma unroll
    for (int t = 0; t < 12; ++t) {
        const int brow = t * 16 + cn;
        short8 b0 = *(const short8*)(sB + brow * 72 + quad * 8);
        short8 b1 = *(const short8*)(sB + brow * 72 + 32 + quad * 8);
        float4v c = {0.f, 0.f, 0.f, 0.f};
        c = __builtin_amdgcn_mfma_f32_16x16x32_bf16(a0, b0, c, 0, 0, 0);
        c = __builtin_amdgcn_mfma_f32_16x16x32_bf16(a1, b1, c, 0, 0, 0);
        acc[t] = c;
    }

    const int orow = n0 + (w << 4) + quad * 4;
#pragma unroll
    for (int t = 0; t < 4; ++t) {
        int o = t * 16 + cn;
        float bqv = bq[o], bkv = bk[o], bvv = bv[o];
        float4v aq = acc[t], ak = acc[4 + t], av = acc[8 + t];
#pragma unroll
        for (int r = 0; r < 4; ++r) {
            size_t base = (size_t)(orow + r) * 64 + o;
            xq[base]  = aq[r] + bqv;
            kvp[base] = (uint_t)f2bf(ak[r] + bkv) | ((uint_t)f2bf(av[r] + bvv) << 16);
        }
    }
}

// ---------------------------------------------------------------------------
// Kernel 2: one wave per 4-point strip; MFMA relation MLP; bf16 LDS tiles
// (no repack); t-broadcast + wgt via LDS; barrier-free; 2-deep gather pipe.
// ---------------------------------------------------------------------------
__global__ __launch_bounds__(256, 4) void k_attn(
    const float* __restrict__ p, const int* __restrict__ idx,
    const float* __restrict__ xq, const uint_t* __restrict__ kvp,
    const float* __restrict__ Wp1, const float* __restrict__ bp1,
    const float* __restrict__ pg, const float* __restrict__ pb,
    const float* __restrict__ pm, const float* __restrict__ pv,
    const float* __restrict__ Wp2, const float* __restrict__ bp2,
    const float* __restrict__ wg1, const float* __restrict__ wb1,
    const float* __restrict__ wm1, const float* __restrict__ wv1,
    const float* __restrict__ Ww1, const float* __restrict__ bw1,
    const float* __restrict__ wg2, const float* __restrict__ wb2,
    const float* __restrict__ wm2, const float* __restrict__ wv2,
    const float* __restrict__ Ww2, const float* __restrict__ bw2,
    float* __restrict__ out)
{
    __shared__ __align__(16) ushort_t swr[4][16 * 72];  // bf16 wrel, stride 72
    __shared__ __align__(16) ushort_t shl[4][16 * 40];  // bf16 h, K-padded, stride 40
    __shared__ __align__(16) float    swt[4][4 * 16 * 4]; // t float4 per (pt,j)
    __shared__ __align__(16) float    swg[4][8 * 20];   // wgtT [m8][j], stride 20

    const int tid   = threadIdx.x;
    const int wid   = __builtin_amdgcn_readfirstlane(tid >> 6);
    const int lane  = tid & 63;
    const int nbase = blockIdx.x * 16 + wid * 4;

    ushort_t* wrelh = swr[wid];
    ushort_t* hLh   = shl[wid];
    float*    stt   = swt[wid];
    float*    wgt   = swg[wid];

    const int cm  = lane & 15;     // MFMA col / row index
    const int q   = lane >> 4;     // quad
    const int m8  = lane & 7;      // share-plane of this lane's channel
    const int cmc = cm & 7;
    const bool colv = cm < 8;

    const int* idxr = idx + (size_t)nbase * 16;     // wave-uniform base

    uint_t ga[16], gb[16];
    auto issueF = [&](int pt, uint_t (&dst)[16]) {
#pragma unroll
        for (int j = 0; j < 16; ++j) {
            int id = __builtin_amdgcn_readfirstlane(idxr[pt * 16 + j]);
            dst[j] = kvp[(size_t)id * 64 + lane];
        }
    };

    // ---- issue kv gathers for pts 0,1 FIRST ----
    issueF(0, ga);
    issueF(1, gb);

    // ---- zero-fill h K-pad region (cols 8..31 stay 0) ----
    {
        uint_t* hz = (uint_t*)hLh;
        for (int i = lane; i < 16 * 20; i += 64) hz[i] = 0u;
    }

    // ---- strip loads ----
    int   idv[4];
    float xqc[4];
#pragma unroll
    for (int pt = 0; pt < 4; ++pt) {
        idv[pt] = idxr[pt * 16 + cm];
        xqc[pt] = xq[(size_t)(nbase + pt) * 64 + lane];
    }
    float gpx[4], gpy[4], gpz[4];
#pragma unroll
    for (int pt = 0; pt < 4; ++pt) {
        gpx[pt] = p[idv[pt] * 3 + 0];
        gpy[pt] = p[idv[pt] * 3 + 1];
        gpz[pt] = p[idv[pt] * 3 + 2];
    }

    // ---- tiny uniform params (linear_p folded BN) ----
    float w100 = Wp1[0], w101 = Wp1[1], w102 = Wp1[2];
    float w110 = Wp1[3], w111 = Wp1[4], w112 = Wp1[5];
    float w120 = Wp1[6], w121 = Wp1[7], w122 = Wp1[8];
    float sp0 = pg[0] * rsqrtf(pv[0] + EPSV);
    float sp1 = pg[1] * rsqrtf(pv[1] + EPSV);
    float sp2 = pg[2] * rsqrtf(pv[2] + EPSV);
    float off0 = (bp1[0] - pm[0]) * sp0 + pb[0];
    float off1 = (bp1[1] - pm[1]) * sp1 + pb[1];
    float off2 = (bp1[2] - pm[2]) * sp2 + pb[2];

    // ---- per-lane params ----
    float s1 = wg1[lane] * rsqrtf(wv1[lane] + EPSV);
    float o1 = wb1[lane] - wm1[lane] * s1;
    float wp2x = Wp2[lane * 3 + 0], wp2y = Wp2[lane * 3 + 1], wp2z = Wp2[lane * 3 + 2];
    float peb = bp2[lane];

    // col params for bn2 (col = cm, valid < 8)
    float s2c = wg2[cmc] * rsqrtf(wv2[cmc] + EPSV);
    float o2c = wb2[cmc] - wm2[cmc] * s2c;
    float bw1c = bw1[cmc];

    // ---- MFMA B-fragments (registers, whole kernel) ----
    short8 bf1a, bf1b, bf2;
    {
        const float* r1 = Ww1 + cmc * 64 + q * 8;
        short8 t1a = packG(r1);
        short8 t1b = packG(r1 + 32);
        short8 t2  = packG(Ww2 + cmc * 8);
        U8 z; z.u = make_uint4(0u, 0u, 0u, 0u);
        bf1a = colv ? t1a : z.s;
        bf1b = colv ? t1b : z.s;
        bf2  = (colv && q == 0) ? t2 : z.s;
    }

    // ---- t-triples per (pt, slot=cm) -> LDS float4 table ----
#pragma unroll
    for (int pt = 0; pt < 4; ++pt) {
        int n = nbase + pt;
        float pcx = p[n * 3 + 0], pcy = p[n * 3 + 1], pcz = p[n * 3 + 2];
        float prx = gpx[pt] - pcx, pry = gpy[pt] - pcy, prz = gpz[pt] - pcz;
        float t0 = fmaxf(fmaf(fmaf(prx, w100, fmaf(pry, w101, prz * w102)), sp0, off0), 0.f);
        float t1 = fmaxf(fmaf(fmaf(prx, w110, fmaf(pry, w111, prz * w112)), sp1, off1), 0.f);
        float t2 = fmaxf(fmaf(fmaf(prx, w120, fmaf(pry, w121, prz * w122)), sp2, off2), 0.f);
        if (lane < 16) {
            float4 tv = make_float4(t0, t1, t2, 0.f);
            *(float4*)(stt + (pt * 16 + cm) * 4) = tv;
        }
    }
    WBAR();

    auto computeF = [&](int pt, uint_t (&g)[16]) {
        float xqv = xqc[pt];
        float vpe[16];
        // ---- Phase A: pe + relation + bn1+relu -> wrel (bf16) ----
#pragma unroll
        for (int j = 0; j < 16; ++j) {
            float4 t = *(const float4*)(stt + (pt * 16 + j) * 4);   // broadcast
            float pe = fmaf(t.x, wp2x, fmaf(t.y, wp2y, fmaf(t.z, wp2z, peb)));
            float xkj = __uint_as_float(g[j] << 16);
            float xvj = __uint_as_float(g[j] & 0xffff0000u);
            vpe[j] = xvj + pe;
            float d = (xkj - xqv) + pe;
            wrelh[j * 72 + lane] = f2bf(fmaxf(fmaf(d, s1, o1), 0.f));
        }
        WBAR();

        // ---- Phase B1 (MFMA): wrel[16x64] @ Ww1^T -> bn2+relu -> hL (bf16) ----
        short8 a1a = *(const short8*)(wrelh + cm * 72 + q * 8);
        short8 a1b = *(const short8*)(wrelh + cm * 72 + 32 + q * 8);
        float4v d1 = {0.f, 0.f, 0.f, 0.f};
        d1 = __builtin_amdgcn_mfma_f32_16x16x32_bf16(a1a, bf1a, d1, 0, 0, 0);
        d1 = __builtin_amdgcn_mfma_f32_16x16x32_bf16(a1b, bf1b, d1, 0, 0, 0);
#pragma unroll
        for (int r = 0; r < 4; ++r) {
            float hv = fmaxf(fmaf(d1[r] + bw1c, s2c, o2c), 0.f);
            if (colv) hLh[(q * 4 + r) * 40 + cm] = f2bf(hv);
        }
        WBAR();

        // ---- Phase B2 (MFMA, K=8 zero-padded): h @ Ww2^T -> logits ----
        short8 a2 = *(const short8*)(hLh + cm * 40 + q * 8);
        float4v d2 = {0.f, 0.f, 0.f, 0.f};
        d2 = __builtin_amdgcn_mfma_f32_16x16x32_bf16(a2, bf2, d2, 0, 0, 0);
        // (bw2 constant over softmax axis -> cancels)

        // ---- Phase C: softmax over j (lane holds 4 j's at col cm) ----
        float mx = fmaxf(fmaxf(d2[0], d2[1]), fmaxf(d2[2], d2[3]));
        mx = fmaxf(mx, __shfl_xor(mx, 16));
        mx = fmaxf(mx, __shfl_xor(mx, 32));
        float e0 = __expf(d2[0] - mx), e1 = __expf(d2[1] - mx);
        float e2 = __expf(d2[2] - mx), e3 = __expf(d2[3] - mx);
        float ss = e0 + e1 + e2 + e3;
        ss += __shfl_xor(ss, 16);
        ss += __shfl_xor(ss, 32);
        float inv = 1.f / ss;
        if (colv) {
            float4 wv4 = make_float4(e0 * inv, e1 * inv, e2 * inv, e3 * inv);
            *(float4*)(wgt + cm * 20 + q * 4) = wv4;   // wgtT[m8=cm][j=4q..]
        }
        WBAR();

        // ---- weighted sum over neighbors (4 b128 broadcast reads) ----
        float acc = 0.f;
#pragma unroll
        for (int gq = 0; gq < 4; ++gq) {
            float4 wv4 = *(const float4*)(wgt + m8 * 20 + gq * 4);
            acc = fmaf(wv4.x, vpe[gq * 4 + 0], acc);
            acc = fmaf(wv4.y, vpe[gq * 4 + 1], acc);
            acc = fmaf(wv4.z, vpe[gq * 4 + 2], acc);
            acc = fmaf(wv4.w, vpe[gq * 4 + 3], acc);
        }
        WBAR();
        out[(size_t)(nbase + pt) * 64 + lane] = acc;
    };

    // 2-deep pipelined strip
    computeF(0, ga);
    issueF(2, ga);
    computeF(1, gb);
    issueF(3, gb);
    computeF(2, ga);
    computeF(3, gb);
}

extern "C" void kernel_launch(void* const* d_in, const int* in_sizes, int n_in,
                              void* d_out, int out_size, void* d_ws, size_t ws_size,
                              hipStream_t stream) {
    const float* p   = (const float*)d_in[0];
    const float* x   = (const float*)d_in[1];
    const int*   idx = (const int*)d_in[2];
    const float* Wq  = (const float*)d_in[3];  const float* bq  = (const float*)d_in[4];
    const float* Wk  = (const float*)d_in[5];  const float* bk  = (const float*)d_in[6];
    const float* Wv  = (const float*)d_in[7];  const float* bv  = (const float*)d_in[8];
    const float* Wp1 = (const float*)d_in[9];  const float* bp1 = (const float*)d_in[10];
    const float* pg  = (const float*)d_in[11]; const float* pb  = (const float*)d_in[12];
    const float* pm  = (const float*)d_in[13]; const float* pv  = (const float*)d_in[14];
    const float* Wp2 = (const float*)d_in[15]; const float* bp2 = (const float*)d_in[16];
    const float* wg1 = (const float*)d_in[17]; const float* wb1 = (const float*)d_in[18];
    const float* wm1 = (const float*)d_in[19]; const float* wv1 = (const float*)d_in[20];
    const float* Ww1 = (const float*)d_in[21]; const float* bw1 = (const float*)d_in[22];
    const float* wg2 = (const float*)d_in[23]; const float* wb2 = (const float*)d_in[24];
    const float* wm2 = (const float*)d_in[25]; const float* wv2 = (const float*)d_in[26];
    const float* Ww2 = (const float*)d_in[27]; const float* bw2 = (const float*)d_in[28];

    float*  xqw = (float*)d_ws;
    uint_t* kvw = (uint_t*)((char*)d_ws + (size_t)NPTS * 64 * sizeof(float));
    float*  outp = (float*)d_out;

    k_qkv<<<dim3(NPTS / 64), dim3(256), 0, stream>>>(x, Wq, bq, Wk, bk, Wv, bv, xqw, kvw);
    k_attn<<<dim3(NPTS / 16), dim3(256), 0, stream>>>(p, idx, xqw, kvw,
                                                      Wp1, bp1, pg, pb, pm, pv, Wp2, bp2,
                                                      wg1, wb1, wm1, wv1, Ww1, bw1,
                                                      wg2, wb2, wm2, wv2, Ww2, bw2, outp);
}